// Round 7
// baseline (250.368 us; speedup 1.0000x reference)
//
#include <hip/hip_runtime.h>

typedef unsigned short u16;
typedef __bf16 bf16x8 __attribute__((ext_vector_type(8)));
typedef float f32x4 __attribute__((ext_vector_type(4)));

__device__ __forceinline__ u16 f2bf(float f) {
    unsigned u = __builtin_bit_cast(unsigned, f);
    u += 0x7fffu + ((u >> 16) & 1u);
    return (u16)(u >> 16);
}
__device__ __forceinline__ float bf2f(u16 h) {
    return __builtin_bit_cast(float, (unsigned)h << 16);
}

#define GLDS16(g, l) __builtin_amdgcn_global_load_lds( \
    (const __attribute__((address_space(1))) void*)(g), \
    (__attribute__((address_space(3))) void*)(l), 16, 0, 0)

#define QK_SCALE 0.044194173824159216f

// ---------------------------------------------------------------------------
// Weight conversion: fp32 -> bf16 (Wq|Wk|Wv stacked, Wp), concat biases.
// ---------------------------------------------------------------------------
__global__ __launch_bounds__(256) void convert_kernel(
    const float* __restrict__ Wq, const float* __restrict__ Wk,
    const float* __restrict__ Wv, const float* __restrict__ Wp,
    const float* __restrict__ bq, const float* __restrict__ bk,
    const float* __restrict__ bv,
    u16* __restrict__ Wqkv, u16* __restrict__ Wpb, float* __restrict__ bqkv)
{
    int idx = blockIdx.x * 256 + threadIdx.x;
    if (idx < 786432) {
        int which = idx >> 18;
        int off   = idx & 262143;
        if (which == 0)
            Wqkv[idx] = f2bf(Wq[off] * QK_SCALE);
        else
            Wqkv[idx] = f2bf(((which == 1) ? Wk : Wv)[off]);
    } else {
        int off = idx - 786432;
        Wpb[off] = f2bf(Wp[off]);
    }
    if (idx < 1536) {
        float bvv = (idx < 512) ? bq[idx] * QK_SCALE
                  : (idx < 1024) ? bk[idx & 511] : bv[idx & 511];
        bqkv[idx] = bvv;
    }
}

// ---------------------------------------------------------------------------
// GroupNorm stats.
// ---------------------------------------------------------------------------
__global__ __launch_bounds__(256) void gn_stats(
    const float* __restrict__ x, float2* __restrict__ stats)
{
    const int g = blockIdx.x, b = blockIdx.y, tid = threadIdx.x;
    const float* xg = x + ((size_t)b * 512 + (size_t)g * 16) * 1024;

    float s = 0.f, s2 = 0.f;
    const float4* x4 = (const float4*)xg;
    #pragma unroll 4
    for (int i = tid; i < 4096; i += 256) {
        float4 v = x4[i];
        s  += v.x + v.y + v.z + v.w;
        s2 += v.x * v.x + v.y * v.y + v.z * v.z + v.w * v.w;
    }
    #pragma unroll
    for (int off = 32; off; off >>= 1) {
        s  += __shfl_down(s, off);
        s2 += __shfl_down(s2, off);
    }
    __shared__ float rs[4], rs2[4];
    const int w = tid >> 6;
    if ((tid & 63) == 0) { rs[w] = s; rs2[w] = s2; }
    __syncthreads();
    if (tid == 0) {
        float S  = rs[0] + rs[1] + rs[2] + rs[3];
        float S2 = rs2[0] + rs2[1] + rs2[2] + rs2[3];
        float mean = S * (1.f / 16384.f);
        float var  = S2 * (1.f / 16384.f) - mean * mean;
        stats[b * 32 + g] = make_float2(mean, rsqrtf(var + 1e-5f));
    }
}

// ---------------------------------------------------------------------------
// GroupNorm apply + transpose: x [B,C,T] fp32 -> ht [B,T,C] bf16.
// ---------------------------------------------------------------------------
__global__ __launch_bounds__(256) void gn_apply(
    const float* __restrict__ x, const float* __restrict__ gamma,
    const float* __restrict__ beta, const float2* __restrict__ stats,
    u16* __restrict__ ht)
{
    const int tc = blockIdx.x, b = blockIdx.y, tid = threadIdx.x;
    const int t0 = tc * 32;

    __shared__ float2 st[32];
    __shared__ float ga[512], be[512];
    __shared__ __align__(16) u16 tile[512 * 32];

    if (tid < 32) st[tid] = stats[b * 32 + tid];
    for (int c = tid; c < 512; c += 256) { ga[c] = gamma[c]; be[c] = beta[c]; }
    __syncthreads();

    #pragma unroll
    for (int pass = 0; pass < 16; pass++) {
        const int c = pass * 32 + (tid >> 3);
        const int f = tid & 7;
        float4 v = *(const float4*)(x + ((size_t)(b * 512 + c)) * 1024 + t0 + f * 4);
        float2 s = st[c >> 4];
        float sc = s.y * ga[c];
        float sh = be[c] - s.x * sc;
        ushort4 hv = {f2bf(v.x * sc + sh), f2bf(v.y * sc + sh),
                      f2bf(v.z * sc + sh), f2bf(v.w * sc + sh)};
        const int slot = f ^ (c & 7) ^ ((c >> 3) & 7);
        *(ushort4*)(tile + c * 32 + slot * 4) = hv;
    }
    __syncthreads();

    #pragma unroll
    for (int p = 0; p < 8; p++) {
        const int t = p * 4 + (tid >> 6);
        const int l = tid & 63;
        u16 tmp[8];
        #pragma unroll
        for (int e = 0; e < 8; e++) {
            const int c = l * 8 + e;
            const int slot = (t >> 2) ^ (c & 7) ^ ((c >> 3) & 7);
            tmp[e] = tile[c * 32 + slot * 4 + (t & 3)];
        }
        *(uint4*)(ht + ((size_t)b * 1024 + t0 + t) * 512 + l * 8) = *(uint4*)tmp;
    }
}

// ---------------------------------------------------------------------------
// Fused flash attention v3: P' = exp(q k^T), O = P'·V, h2 = O / rowsum(P').
// One block per (batch, 64-row Q-tile); grid 256 (1/CU), 1024 thr = 16 waves.
// v3 change (LDS-throughput fix): GEMM-A runs 2 s-chains per wave
// (sacc[2][4]) so each 1024B Q-fragment LDS read feeds 8 MFMAs (was 4) --
// halves Q LDS traffic.  KVBLK = 512 (16 waves x 32 s-rows), st loop = 2,
// P single 64KB buffer [64 t][512 s] (granule ^ (t&7) swizzle); WAR on P
// guarded by __syncthreads() after GEMM-B.
// K,V read directly from global (L2-resident), 1-deep register prefetch.
// LDS: Qs 64KB @0 | P 64KB @65536B | rl 4KB + rinv @131072B.
// ---------------------------------------------------------------------------
__global__ __launch_bounds__(1024) void flash64(
    const u16* __restrict__ q,   // [B,T,C] bf16
    const u16* __restrict__ k,   // [B,T,C] bf16
    const u16* __restrict__ v,   // [B,C,T] bf16
    u16* __restrict__ o)         // [B,T,C] bf16
{
    __shared__ __align__(16) u16 smem[67712];   // 135424 B

    const int tid  = threadIdx.x;
    const int lane = tid & 63;
    const int wave = tid >> 6;          // 0..15
    const int l15  = lane & 15;
    const int lh   = lane >> 4;         // 0..3
    const int r7   = l15 & 7;

    // block -> (b, qtile): XCD i (= flat%8) serves batches {2i, 2i+1}
    const int flat  = blockIdx.x;
    const int b     = ((flat & 7) << 1) | (flat >> 7);
    const int qtile = (flat >> 3) & 15;
    const int t0    = qtile * 64;

    const u16* Qg = q + ((size_t)b * 1024 + t0) * 512;
    const u16* Kg = k + (size_t)b * 524288;
    const u16* Vg = v + (size_t)b * 524288;
    u16*       Og = o + ((size_t)b * 1024 + t0) * 512;

    // ---- stage Q to LDS: 4 rows per wave (1024B each), granule-8 XOR swizzle
    #pragma unroll
    for (int u = 0; u < 4; u++) {
        const int r0 = wave + 16 * u;                // row 0..63
        GLDS16(Qg + r0 * 512 + (lane ^ (r0 & 7)) * 8,
               smem + r0 * 512 + lane * 8);
    }
    asm volatile("s_waitcnt vmcnt(0)" ::: "memory");
    __syncthreads();

    u16* Pc = smem + 32768;      // P'[64 t][512 s], 1024 B/row, single buffer
    f32x4 oacc[2][4] = {};       // [mi over c][nj over t]
    float rs_[4] = {};           // per-nj (t) partial row sums

    for (int st = 0; st < 2; st++) {
        // ---- GEMM-A: S^T[s:512][t:64], wave owns 32 s-rows (2 chains) ----
        f32x4 sacc[2][4] = {};
        const u16* Krow0 = Kg + (size_t)(st * 512 + wave * 32 + l15) * 512 + lh * 8;
        const u16* Krow1 = Krow0 + 16 * 512;
        bf16x8 k0 = *(const bf16x8*)(Krow0);
        bf16x8 k1 = *(const bf16x8*)(Krow1);
        #pragma unroll
        for (int i = 0; i < 16; i++) {               // k0dim = i*32
            bf16x8 n0, n1;
            if (i < 15) {
                n0 = *(const bf16x8*)(Krow0 + (i + 1) * 32);
                n1 = *(const bf16x8*)(Krow1 + (i + 1) * 32);
            }
            bf16x8 qf[4];
            #pragma unroll
            for (int nj = 0; nj < 4; nj++)
                qf[nj] = *(const bf16x8*)(smem + (nj * 16 + l15) * 512 +
                                          (((i * 4 + lh) ^ r7) << 3));
            __builtin_amdgcn_s_setprio(1);
            #pragma unroll
            for (int nj = 0; nj < 4; nj++) {
                sacc[0][nj] = __builtin_amdgcn_mfma_f32_16x16x32_bf16(
                    k0, qf[nj], sacc[0][nj], 0, 0, 0);
                sacc[1][nj] = __builtin_amdgcn_mfma_f32_16x16x32_bf16(
                    k1, qf[nj], sacc[1][nj], 0, 0, 0);
            }
            __builtin_amdgcn_s_setprio(0);
            if (i < 15) { k0 = n0; k1 = n1; }
        }

        // ---- exp + rsum + vectorized P' write ----
        // lane holds s = wave*32 + si*16 + lh*4 + r  at  t = nj*16 + l15
        #pragma unroll
        for (int si = 0; si < 2; si++) {
            const int sb = wave * 32 + si * 16 + lh * 4;   // mult of 4
            const int g  = sb >> 3;                        // granule 0..63
            const int gb = (sb & 7) * 2;                   // 0 or 8
            #pragma unroll
            for (int nj = 0; nj < 4; nj++) {
                const int t = nj * 16 + l15;
                u16 hv[4];
                #pragma unroll
                for (int r = 0; r < 4; r++) {
                    float e = __expf(sacc[si][nj][r]);
                    u16 h = f2bf(e);
                    rs_[nj] += bf2f(h);                    // sum ROUNDED P'
                    hv[r] = h;
                }
                *(ushort4*)((char*)Pc + t * 1024 + ((g ^ (t & 7)) << 4) + gb)
                    = *(ushort4*)hv;
            }
        }
        asm volatile("s_waitcnt lgkmcnt(0)" ::: "memory");
        __builtin_amdgcn_s_barrier();                // P'(st) visible to all

        // ---- GEMM-B: O^T += mfma(V, P'), wave owns 32 c-rows ----
        const u16* Vrow0 = Vg + (size_t)(wave * 32 + l15) * 1024 + st * 512 + lh * 8;
        const u16* Vrow1 = Vrow0 + 16 * 1024;
        bf16x8 va0 = *(const bf16x8*)(Vrow0);
        bf16x8 va1 = *(const bf16x8*)(Vrow1);
        #pragma unroll
        for (int j = 0; j < 16; j++) {               // s0 = j*32
            bf16x8 na0, na1;
            if (j < 15) {
                na0 = *(const bf16x8*)(Vrow0 + (j + 1) * 32);
                na1 = *(const bf16x8*)(Vrow1 + (j + 1) * 32);
            }
            bf16x8 pb[4];
            #pragma unroll
            for (int nj = 0; nj < 4; nj++) {
                const int t = nj * 16 + l15;
                pb[nj] = *(const bf16x8*)((char*)Pc + t * 1024 +
                                          (((j * 4 + lh) ^ (t & 7)) << 4));
            }
            __builtin_amdgcn_s_setprio(1);
            #pragma unroll
            for (int nj = 0; nj < 4; nj++) {
                oacc[0][nj] = __builtin_amdgcn_mfma_f32_16x16x32_bf16(
                    va0, pb[nj], oacc[0][nj], 0, 0, 0);
                oacc[1][nj] = __builtin_amdgcn_mfma_f32_16x16x32_bf16(
                    va1, pb[nj], oacc[1][nj], 0, 0, 0);
            }
            __builtin_amdgcn_s_setprio(0);
            if (j < 15) { va0 = na0; va1 = na1; }
        }
        __syncthreads();     // all waves done reading P' before next st write
    }

    // ---- rsum reduce across lanes (lh) and waves ----
    float* rl   = (float*)(smem + 65536);            // [16 waves][64 t]
    float* rinv = rl + 1024;
    #pragma unroll
    for (int nj = 0; nj < 4; nj++) {
        rs_[nj] += __shfl_xor(rs_[nj], 16);
        rs_[nj] += __shfl_xor(rs_[nj], 32);
    }
    if (lane < 16) {
        #pragma unroll
        for (int nj = 0; nj < 4; nj++)
            rl[wave * 64 + nj * 16 + lane] = rs_[nj];
    }
    __syncthreads();
    if (tid < 64) {
        float tot = 0.f;
        #pragma unroll
        for (int w = 0; w < 16; w++) tot += rl[w * 64 + tid];
        rinv[tid] = 1.0f / tot;
    }
    __syncthreads();

    // ---- scale + stage O[t][c] to LDS (Qs region, dead) + coalesced store
    float ri_[4];
    #pragma unroll
    for (int nj = 0; nj < 4; nj++) ri_[nj] = rinv[nj * 16 + l15];

    #pragma unroll
    for (int mi = 0; mi < 2; mi++) {
        const int cb  = wave * 32 + mi * 16 + lh * 4;   // c base (mult of 4)
        const int gsl = cb >> 3;
        const int ghl = (cb & 7) * 2;
        #pragma unroll
        for (int nj = 0; nj < 4; nj++) {
            const int t = nj * 16 + l15;
            ushort4 hv = {f2bf(oacc[mi][nj][0] * ri_[nj]),
                          f2bf(oacc[mi][nj][1] * ri_[nj]),
                          f2bf(oacc[mi][nj][2] * ri_[nj]),
                          f2bf(oacc[mi][nj][3] * ri_[nj])};
            *(ushort4*)((char*)smem + t * 1024 + ((gsl ^ (t & 7)) << 4) + ghl) = hv;
        }
    }
    __syncthreads();
    #pragma unroll
    for (int p = 0; p < 4; p++) {
        const int t  = p * 16 + (tid >> 6);
        const int gi = tid & 63;
        uint4 v4 = *(const uint4*)((char*)smem + t * 1024 + ((gi ^ (t & 7)) << 4));
        *(uint4*)(Og + t * 512 + gi * 8) = v4;
    }
}

// ---------------------------------------------------------------------------
// Pipelined NT GEMM (r4, proven): BM=256 BN=128 BK=64, 8 waves, 3 LDS bufs,
// counted vmcnt(6), 1 barrier/K-tile, 2 ks-phases, setprio around MFMA.
// MODE 0: qkv (q,k [B,T,C] direct; v [B,C,T] LDS-transpose) +bias
// MODE 3: fp32 out[B,C,T] = acc + bias[n] + x, LDS-transpose
// ---------------------------------------------------------------------------
template <int MODE>
__global__ __launch_bounds__(512, 2) void gemm_nt(
    const u16* __restrict__ A, const u16* __restrict__ B,
    size_t strideA, size_t strideB, int lda, int ldb, int K,
    u16* __restrict__ o0, u16* __restrict__ o1, u16* __restrict__ o2,
    float* __restrict__ fo, const float* __restrict__ bias,
    const float* __restrict__ xres)
{
    __shared__ __align__(16) u16 smem[73728];   // 144 KB
    u16* As = smem;                  // 3 x 16384 elems (256x64)
    u16* Bs = smem + 49152;          // 3 x  8192 elems (128x64)

    const int tid  = threadIdx.x;
    const int lane = tid & 63;
    const int wave = tid >> 6;
    const int wm   = (wave & 3) * 64;
    const int wn   = (wave >> 2) * 64;

    const int gx = gridDim.x, gy = gridDim.y;
    int f = blockIdx.x + gx * (blockIdx.y + gy * blockIdx.z);
    const int nwg = gx * gy * (int)gridDim.z;
    f = (f & 7) * (nwg >> 3) + (f >> 3);
    const int bx  = f % gx;
    const int byz = f / gx;
    const int by  = byz % gy;
    const int b   = byz / gy;

    const u16* Ab = A + (size_t)b * strideA + (size_t)by * 256 * lda;
    const u16* Bb = B + (size_t)b * strideB + (size_t)bx * 128 * ldb;

    const int srow = tid >> 3;
    const int sc   = tid & 7;
    const int scg  = sc ^ (srow & 7);

    const u16* aSrc[4]; int aDst[4];
    #pragma unroll
    for (int u = 0; u < 4; u++) {
        aSrc[u] = Ab + (size_t)(u * 64 + srow) * lda + scg * 8;
        aDst[u] = (u * 64 + srow) * 64 + sc * 8;
    }
    const u16* bSrc[2]; int bDst[2];
    #pragma unroll
    for (int u = 0; u < 2; u++) {
        bSrc[u] = Bb + (size_t)(u * 64 + srow) * ldb + scg * 8;
        bDst[u] = (u * 64 + srow) * 64 + sc * 8;
    }

    const int l15 = lane & 15, lh = lane >> 4, rx = lane & 7;
    int aOff[4][2], bOff[4][2];
    #pragma unroll
    for (int i = 0; i < 4; i++)
        #pragma unroll
        for (int ks = 0; ks < 2; ks++) {
            const int slot = ((ks << 2) + lh) ^ rx;
            aOff[i][ks] = (wm + i * 16 + l15) * 64 + slot * 8;
            bOff[i][ks] = (wn + i * 16 + l15) * 64 + slot * 8;
        }

    f32x4 acc[4][4] = {};
    const int NT = K >> 6;

    #pragma unroll
    for (int u = 0; u < 4; u++) GLDS16(aSrc[u], As + aDst[u]);
    #pragma unroll
    for (int u = 0; u < 2; u++) GLDS16(bSrc[u], Bs + bDst[u]);
    #pragma unroll
    for (int u = 0; u < 4; u++) GLDS16(aSrc[u] + 64, As + 16384 + aDst[u]);
    #pragma unroll
    for (int u = 0; u < 2; u++) GLDS16(bSrc[u] + 64, Bs + 8192 + bDst[u]);

    int cbuf = 0, sbuf = 2;
    for (int t = 0; t < NT; ++t) {
        if (t == NT - 1) asm volatile("s_waitcnt vmcnt(0)" ::: "memory");
        else             asm volatile("s_waitcnt vmcnt(6)" ::: "memory");
        __builtin_amdgcn_s_barrier();

        const u16* Ac = As + cbuf * 16384;
        const u16* Bc = Bs + cbuf * 8192;
        u16* Asb = As + sbuf * 16384;
        u16* Bsb = Bs + sbuf * 8192;
        const int ko = (t + 2) * 64;
        const bool pf = (t + 2 < NT);

        if (pf) {
            GLDS16(aSrc[0] + ko, Asb + aDst[0]);
            GLDS16(aSrc[1] + ko, Asb + aDst[1]);
            GLDS16(bSrc[0] + ko, Bsb + bDst[0]);
        }
        {
            bf16x8 af[4], bfr[4];
            #pragma unroll
            for (int i = 0; i < 4; i++) {
                af[i]  = *(const bf16x8*)(Ac + aOff[i][0]);
                bfr[i] = *(const bf16x8*)(Bc + bOff[i][0]);
            }
            __builtin_amdgcn_s_setprio(1);
            #pragma unroll
            for (int mi = 0; mi < 4; mi++)
                #pragma unroll
                for (int nj = 0; nj < 4; nj++)
                    acc[mi][nj] = __builtin_amdgcn_mfma_f32_16x16x32_bf16(
                        af[mi], bfr[nj], acc[mi][nj], 0, 0, 0);
            __builtin_amdgcn_s_setprio(0);
        }
        if (pf) {
            GLDS16(aSrc[2] + ko, Asb + aDst[2]);
            GLDS16(aSrc[3] + ko, Asb + aDst[3]);
            GLDS16(bSrc[1] + ko, Bsb + bDst[1]);
        }
        {
            bf16x8 af[4], bfr[4];
            #pragma unroll
            for (int i = 0; i < 4; i++) {
                af[i]  = *(const bf16x8*)(Ac + aOff[i][1]);
                bfr[i] = *(const bf16x8*)(Bc + bOff[i][1]);
            }
            __builtin_amdgcn_s_setprio(1);
            #pragma unroll
            for (int mi = 0; mi < 4; mi++)
                #pragma unroll
                for (int nj = 0; nj < 4; nj++)
                    acc[mi][nj] = __builtin_amdgcn_mfma_f32_16x16x32_bf16(
                        af[mi], bfr[nj], acc[mi][nj], 0, 0, 0);
            __builtin_amdgcn_s_setprio(0);
        }

        cbuf = (cbuf == 2) ? 0 : cbuf + 1;
        sbuf = (sbuf == 2) ? 0 : sbuf + 1;
    }

    const int N0 = bx * 128;
    const int M0 = by * 256;

    if (MODE == 0 && N0 < 1024) {
        u16* dst = (N0 < 512) ? o0 : o1;
        const int nn0 = N0 & 511;
        #pragma unroll
        for (int nj = 0; nj < 4; nj++) {
            const int n = wn + nj * 16 + l15;
            const float bv = bias[N0 + n];
            #pragma unroll
            for (int mi = 0; mi < 4; mi++) {
                const int mq = M0 + wm + mi * 16 + lh * 4;
                const size_t base = ((size_t)b * 1024 + mq) * 512 + nn0 + n;
                dst[base]        = f2bf(acc[mi][nj][0] + bv);
                dst[base + 512]  = f2bf(acc[mi][nj][1] + bv);
                dst[base + 1024] = f2bf(acc[mi][nj][2] + bv);
                dst[base + 1536] = f2bf(acc[mi][nj][3] + bv);
            }
        }
    } else if (MODE == 0) {
        // v: [B,C,T] via LDS transpose, 512B-row coalesced stores
        __syncthreads();
        #pragma unroll
        for (int mi = 0; mi < 4; mi++) {
            const int mq = wm + mi * 16 + lh * 4;
            #pragma unroll
            for (int nj = 0; nj < 4; nj++) {
                const int n = wn + nj * 16 + l15;
                const float bv = bias[N0 + n];
                ushort4 hv = {f2bf(acc[mi][nj][0] + bv), f2bf(acc[mi][nj][1] + bv),
                              f2bf(acc[mi][nj][2] + bv), f2bf(acc[mi][nj][3] + bv)};
                *(ushort4*)((char*)smem + n * 512 +
                            (((mq >> 3) ^ (n & 31)) << 4) + ((mq >> 2) & 1) * 8) = hv;
            }
        }
        __syncthreads();
        #pragma unroll
        for (int p = 0; p < 8; p++) {
            const int n  = p * 16 + (tid >> 5);
            const int gi = tid & 31;
            uint4 v4 = *(const uint4*)((char*)smem + n * 512 +
                                       ((gi ^ (n & 31)) << 4));
            u16* dst = o2 + ((size_t)b * 512 + (N0 - 1024) + n) * 1024 + M0;
            *(uint4*)(dst + gi * 8) = v4;
        }
    } else {
        // MODE 3: fp32 [n:128][m:256] tile, +bias +residual
        __syncthreads();
        float* smf = (float*)smem;
        #pragma unroll
        for (int mi = 0; mi < 4; mi++) {
            const int mq = wm + mi * 16 + lh * 4;
            #pragma unroll
            for (int nj = 0; nj < 4; nj++) {
                const int n = wn + nj * 16 + l15;
                float4 v4 = {acc[mi][nj][0], acc[mi][nj][1],
                             acc[mi][nj][2], acc[mi][nj][3]};
                *(float4*)((char*)smf + n * 1024 +
                           (((mq >> 2) ^ (n & 63)) << 4)) = v4;
            }
        }
        __syncthreads();
        #pragma unroll
        for (int p = 0; p < 16; p++) {
            const int n  = p * 8 + (tid >> 6);
            const int gi = tid & 63;
            float4 v4 = *(const float4*)((char*)smf + n * 1024 +
                                         ((gi ^ (n & 63)) << 4));
            const size_t off = ((size_t)b * 512 + N0 + n) * 1024 + M0 + gi * 4;
            const float bv = bias[N0 + n];
            const float4 xv = *(const float4*)(xres + off);
            float4 ov = {v4.x + bv + xv.x, v4.y + bv + xv.y,
                         v4.z + bv + xv.z, v4.w + bv + xv.w};
            *(float4*)(fo + off) = ov;
        }
    }
}

// ---------------------------------------------------------------------------
extern "C" void kernel_launch(void* const* d_in, const int* in_sizes, int n_in,
                              void* d_out, int out_size, void* d_ws, size_t ws_size,
                              hipStream_t stream)
{
    const float* x     = (const float*)d_in[0];
    const float* gamma = (const float*)d_in[1];
    const float* beta  = (const float*)d_in[2];
    const float* Wq    = (const float*)d_in[3];
    const float* bq    = (const float*)d_in[4];
    const float* Wk    = (const float*)d_in[5];
    const float* bk    = (const float*)d_in[6];
    const float* Wv    = (const float*)d_in[7];
    const float* bv    = (const float*)d_in[8];
    const float* Wp    = (const float*)d_in[9];
    const float* bp    = (const float*)d_in[10];

    char* ws = (char*)d_ws;
    u16*   Wqkv   = (u16*)(ws + 0);           //  1,572,864 B
    u16*   Wpb    = (u16*)(ws + 1572864);     //    524,288 B
    float* bqkv   = (float*)(ws + 2097152);   //      8,192 B
    u16*   ht     = (u16*)(ws + 2105344);     // 16,777,216 B (reused as h2)
    u16*   kt     = (u16*)(ws + 18882560);    // 16,777,216 B
    u16*   vv     = (u16*)(ws + 35659776);    // 16,777,216 B
    u16*   qt  = (u16*)d_out;   // scratch: q [B,T,C] bf16 (first 16.8MB)
    float2* stats = (float2*)((char*)d_out + 16777216);  // 4KB scratch
    u16*   h2  = ht;
    float* out = (float*)d_out;

    convert_kernel<<<4096, 256, 0, stream>>>(Wq, Wk, Wv, Wp, bq, bk, bv,
                                             Wqkv, Wpb, bqkv);
    gn_stats<<<dim3(32, 16), 256, 0, stream>>>(x, stats);
    gn_apply<<<dim3(32, 16), 256, 0, stream>>>(x, gamma, beta, stats, ht);

    // GEMM1 qkv: M=1024(T) N=1536(3C) K=512 ; A=ht[B,T,C], B=Wqkv[3C,C]
    gemm_nt<0><<<dim3(12, 4, 16), 512, 0, stream>>>(
        ht, Wqkv, 524288, 0, 512, 512, 512,
        qt, kt, vv, nullptr, bqkv, nullptr);

    // Fused attention: scores + softmax + PV -> h2 [B,T,C]
    flash64<<<256, 1024, 0, stream>>>(qt, kt, vv, h2);

    // GEMM4 proj+residual: M=1024(T) N=512(C) K=512 ; A=h2, B=Wp
    gemm_nt<3><<<dim3(4, 4, 16), 512, 0, stream>>>(
        h2, Wpb, 524288, 0, 512, 512, 512,
        nullptr, nullptr, nullptr, out, bp, x);
}

// Round 8
// 227.085 us; speedup vs baseline: 1.1025x; 1.1025x over previous
//
#include <hip/hip_runtime.h>

typedef unsigned short u16;
typedef __bf16 bf16x8 __attribute__((ext_vector_type(8)));
typedef float f32x4 __attribute__((ext_vector_type(4)));
typedef float f32x16 __attribute__((ext_vector_type(16)));

__device__ __forceinline__ u16 f2bf(float f) {
    unsigned u = __builtin_bit_cast(unsigned, f);
    u += 0x7fffu + ((u >> 16) & 1u);
    return (u16)(u >> 16);
}
__device__ __forceinline__ float bf2f(u16 h) {
    return __builtin_bit_cast(float, (unsigned)h << 16);
}

#define GLDS16(g, l) __builtin_amdgcn_global_load_lds( \
    (const __attribute__((address_space(1))) void*)(g), \
    (__attribute__((address_space(3))) void*)(l), 16, 0, 0)

#define QK_SCALE 0.044194173824159216f

// ---------------------------------------------------------------------------
// Weight conversion + rsum zero-init.
// ---------------------------------------------------------------------------
__global__ __launch_bounds__(256) void convert_kernel(
    const float* __restrict__ Wq, const float* __restrict__ Wk,
    const float* __restrict__ Wv, const float* __restrict__ Wp,
    const float* __restrict__ bq, const float* __restrict__ bk,
    const float* __restrict__ bv,
    u16* __restrict__ Wqkv, u16* __restrict__ Wpb, float* __restrict__ bqkv,
    float* __restrict__ rsum)
{
    int idx = blockIdx.x * 256 + threadIdx.x;
    if (idx < 786432) {
        int which = idx >> 18;
        int off   = idx & 262143;
        if (which == 0)
            Wqkv[idx] = f2bf(Wq[off] * QK_SCALE);
        else
            Wqkv[idx] = f2bf(((which == 1) ? Wk : Wv)[off]);
    } else {
        int off = idx - 786432;
        Wpb[off] = f2bf(Wp[off]);
    }
    if (idx < 1536) {
        float bvv = (idx < 512) ? bq[idx] * QK_SCALE
                  : (idx < 1024) ? bk[idx & 511] : bv[idx & 511];
        bqkv[idx] = bvv;
    }
    if (idx < 16384) rsum[idx] = 0.f;
}

// ---------------------------------------------------------------------------
// GroupNorm stats: one block per (group, batch) -> (mean, rstd)
// ---------------------------------------------------------------------------
__global__ __launch_bounds__(256) void gn_stats(
    const float* __restrict__ x, float2* __restrict__ stats)
{
    const int g = blockIdx.x, b = blockIdx.y, tid = threadIdx.x;
    const float* xg = x + ((size_t)b * 512 + (size_t)g * 16) * 1024;

    float s = 0.f, s2 = 0.f;
    const float4* x4 = (const float4*)xg;
    #pragma unroll 4
    for (int i = tid; i < 4096; i += 256) {
        float4 v = x4[i];
        s  += v.x + v.y + v.z + v.w;
        s2 += v.x * v.x + v.y * v.y + v.z * v.z + v.w * v.w;
    }
    #pragma unroll
    for (int off = 32; off; off >>= 1) {
        s  += __shfl_down(s, off);
        s2 += __shfl_down(s2, off);
    }
    __shared__ float rs[4], rs2[4];
    const int w = tid >> 6;
    if ((tid & 63) == 0) { rs[w] = s; rs2[w] = s2; }
    __syncthreads();
    if (tid == 0) {
        float S  = rs[0] + rs[1] + rs[2] + rs[3];
        float S2 = rs2[0] + rs2[1] + rs2[2] + rs2[3];
        float mean = S * (1.f / 16384.f);
        float var  = S2 * (1.f / 16384.f) - mean * mean;
        stats[b * 32 + g] = make_float2(mean, rsqrtf(var + 1e-5f));
    }
}

// ---------------------------------------------------------------------------
// GroupNorm apply + transpose: x [B,C,T] fp32 -> ht [B,T,C] bf16.
// ---------------------------------------------------------------------------
__global__ __launch_bounds__(256) void gn_apply(
    const float* __restrict__ x, const float* __restrict__ gamma,
    const float* __restrict__ beta, const float2* __restrict__ stats,
    u16* __restrict__ ht)
{
    const int tc = blockIdx.x, b = blockIdx.y, tid = threadIdx.x;
    const int t0 = tc * 32;

    __shared__ float2 st[32];
    __shared__ float ga[512], be[512];
    __shared__ __align__(16) u16 tile[512 * 32];

    if (tid < 32) st[tid] = stats[b * 32 + tid];
    for (int c = tid; c < 512; c += 256) { ga[c] = gamma[c]; be[c] = beta[c]; }
    __syncthreads();

    #pragma unroll
    for (int pass = 0; pass < 16; pass++) {
        const int c = pass * 32 + (tid >> 3);
        const int f = tid & 7;
        float4 v = *(const float4*)(x + ((size_t)(b * 512 + c)) * 1024 + t0 + f * 4);
        float2 s = st[c >> 4];
        float sc = s.y * ga[c];
        float sh = be[c] - s.x * sc;
        ushort4 hv = {f2bf(v.x * sc + sh), f2bf(v.y * sc + sh),
                      f2bf(v.z * sc + sh), f2bf(v.w * sc + sh)};
        const int slot = f ^ (c & 7) ^ ((c >> 3) & 7);
        *(ushort4*)(tile + c * 32 + slot * 4) = hv;
    }
    __syncthreads();

    #pragma unroll
    for (int p = 0; p < 8; p++) {
        const int t = p * 4 + (tid >> 6);
        const int l = tid & 63;
        u16 tmp[8];
        #pragma unroll
        for (int e = 0; e < 8; e++) {
            const int c = l * 8 + e;
            const int slot = (t >> 2) ^ (c & 7) ^ ((c >> 3) & 7);
            tmp[e] = tile[c * 32 + slot * 4 + (t & 3)];
        }
        *(uint4*)(ht + ((size_t)b * 1024 + t0 + t) * 512 + l * 8) = *(uint4*)tmp;
    }
}

// ---------------------------------------------------------------------------
// Pipelined NT GEMM (r4-proven, used for GEMM1 only): BM=256 BN=128 BK=64,
// 8 waves, 3 LDS bufs, counted vmcnt(6), 1 barrier/K-tile, 2 ks-phases,
// setprio around MFMA.  MODE 0: qkv (q,k [B,T,C] direct; v [B,C,T]
// LDS-transpose) + bias.
// ---------------------------------------------------------------------------
template <int MODE>
__global__ __launch_bounds__(512, 2) void gemm_big(
    const u16* __restrict__ A, const u16* __restrict__ B,
    size_t strideA, size_t strideB, int lda, int ldb, int K,
    u16* __restrict__ o0, u16* __restrict__ o1, u16* __restrict__ o2,
    const float* __restrict__ bias)
{
    __shared__ __align__(16) u16 smem[73728];   // 144 KB
    u16* As = smem;                  // 3 x 16384 elems (256x64)
    u16* Bs = smem + 49152;          // 3 x  8192 elems (128x64)

    const int tid  = threadIdx.x;
    const int lane = tid & 63;
    const int wave = tid >> 6;
    const int wm   = (wave & 3) * 64;
    const int wn   = (wave >> 2) * 64;

    const int gx = gridDim.x, gy = gridDim.y;
    int f = blockIdx.x + gx * (blockIdx.y + gy * blockIdx.z);
    const int nwg = gx * gy * (int)gridDim.z;
    f = (f & 7) * (nwg >> 3) + (f >> 3);
    const int bx  = f % gx;
    const int byz = f / gx;
    const int by  = byz % gy;
    const int b   = byz / gy;

    const u16* Ab = A + (size_t)b * strideA + (size_t)by * 256 * lda;
    const u16* Bb = B + (size_t)b * strideB + (size_t)bx * 128 * ldb;

    const int srow = tid >> 3;
    const int sc   = tid & 7;
    const int scg  = sc ^ (srow & 7);

    const u16* aSrc[4]; int aDst[4];
    #pragma unroll
    for (int u = 0; u < 4; u++) {
        aSrc[u] = Ab + (size_t)(u * 64 + srow) * lda + scg * 8;
        aDst[u] = (u * 64 + srow) * 64 + sc * 8;
    }
    const u16* bSrc[2]; int bDst[2];
    #pragma unroll
    for (int u = 0; u < 2; u++) {
        bSrc[u] = Bb + (size_t)(u * 64 + srow) * ldb + scg * 8;
        bDst[u] = (u * 64 + srow) * 64 + sc * 8;
    }

    const int l15 = lane & 15, lh = lane >> 4, rx = lane & 7;
    int aOff[4][2], bOff[4][2];
    #pragma unroll
    for (int i = 0; i < 4; i++)
        #pragma unroll
        for (int ks = 0; ks < 2; ks++) {
            const int slot = ((ks << 2) + lh) ^ rx;
            aOff[i][ks] = (wm + i * 16 + l15) * 64 + slot * 8;
            bOff[i][ks] = (wn + i * 16 + l15) * 64 + slot * 8;
        }

    f32x4 acc[4][4] = {};
    const int NT = K >> 6;

    #pragma unroll
    for (int u = 0; u < 4; u++) GLDS16(aSrc[u], As + aDst[u]);
    #pragma unroll
    for (int u = 0; u < 2; u++) GLDS16(bSrc[u], Bs + bDst[u]);
    #pragma unroll
    for (int u = 0; u < 4; u++) GLDS16(aSrc[u] + 64, As + 16384 + aDst[u]);
    #pragma unroll
    for (int u = 0; u < 2; u++) GLDS16(bSrc[u] + 64, Bs + 8192 + bDst[u]);

    int cbuf = 0, sbuf = 2;
    for (int t = 0; t < NT; ++t) {
        if (t == NT - 1) asm volatile("s_waitcnt vmcnt(0)" ::: "memory");
        else             asm volatile("s_waitcnt vmcnt(6)" ::: "memory");
        __builtin_amdgcn_s_barrier();

        const u16* Ac = As + cbuf * 16384;
        const u16* Bc = Bs + cbuf * 8192;
        u16* Asb = As + sbuf * 16384;
        u16* Bsb = Bs + sbuf * 8192;
        const int ko = (t + 2) * 64;
        const bool pf = (t + 2 < NT);

        if (pf) {
            GLDS16(aSrc[0] + ko, Asb + aDst[0]);
            GLDS16(aSrc[1] + ko, Asb + aDst[1]);
            GLDS16(bSrc[0] + ko, Bsb + bDst[0]);
        }
        {
            bf16x8 af[4], bfr[4];
            #pragma unroll
            for (int i = 0; i < 4; i++) {
                af[i]  = *(const bf16x8*)(Ac + aOff[i][0]);
                bfr[i] = *(const bf16x8*)(Bc + bOff[i][0]);
            }
            __builtin_amdgcn_s_setprio(1);
            #pragma unroll
            for (int mi = 0; mi < 4; mi++)
                #pragma unroll
                for (int nj = 0; nj < 4; nj++)
                    acc[mi][nj] = __builtin_amdgcn_mfma_f32_16x16x32_bf16(
                        af[mi], bfr[nj], acc[mi][nj], 0, 0, 0);
            __builtin_amdgcn_s_setprio(0);
        }
        if (pf) {
            GLDS16(aSrc[2] + ko, Asb + aDst[2]);
            GLDS16(aSrc[3] + ko, Asb + aDst[3]);
            GLDS16(bSrc[1] + ko, Bsb + bDst[1]);
        }
        {
            bf16x8 af[4], bfr[4];
            #pragma unroll
            for (int i = 0; i < 4; i++) {
                af[i]  = *(const bf16x8*)(Ac + aOff[i][1]);
                bfr[i] = *(const bf16x8*)(Bc + bOff[i][1]);
            }
            __builtin_amdgcn_s_setprio(1);
            #pragma unroll
            for (int mi = 0; mi < 4; mi++)
                #pragma unroll
                for (int nj = 0; nj < 4; nj++)
                    acc[mi][nj] = __builtin_amdgcn_mfma_f32_16x16x32_bf16(
                        af[mi], bfr[nj], acc[mi][nj], 0, 0, 0);
            __builtin_amdgcn_s_setprio(0);
        }

        cbuf = (cbuf == 2) ? 0 : cbuf + 1;
        sbuf = (sbuf == 2) ? 0 : sbuf + 1;
    }

    const int N0 = bx * 128;
    const int M0 = by * 256;

    if (N0 < 1024) {
        // q or k: [B,T,C] direct scalar stores; block covers full 128-n span
        u16* dst = (N0 < 512) ? o0 : o1;
        const int nn0 = N0 & 511;
        #pragma unroll
        for (int nj = 0; nj < 4; nj++) {
            const int n = wn + nj * 16 + l15;
            const float bv = bias[N0 + n];
            #pragma unroll
            for (int mi = 0; mi < 4; mi++) {
                const int mq = M0 + wm + mi * 16 + lh * 4;
                const size_t base = ((size_t)b * 1024 + mq) * 512 + nn0 + n;
                dst[base]        = f2bf(acc[mi][nj][0] + bv);
                dst[base + 512]  = f2bf(acc[mi][nj][1] + bv);
                dst[base + 1024] = f2bf(acc[mi][nj][2] + bv);
                dst[base + 1536] = f2bf(acc[mi][nj][3] + bv);
            }
        }
    } else {
        // v: [B,C,T] via LDS transpose, 512B-row coalesced stores
        __syncthreads();
        #pragma unroll
        for (int mi = 0; mi < 4; mi++) {
            const int mq = wm + mi * 16 + lh * 4;
            #pragma unroll
            for (int nj = 0; nj < 4; nj++) {
                const int n = wn + nj * 16 + l15;
                const float bv = bias[N0 + n];
                ushort4 hv = {f2bf(acc[mi][nj][0] + bv), f2bf(acc[mi][nj][1] + bv),
                              f2bf(acc[mi][nj][2] + bv), f2bf(acc[mi][nj][3] + bv)};
                *(ushort4*)((char*)smem + n * 512 +
                            (((mq >> 3) ^ (n & 31)) << 4) + ((mq >> 2) & 1) * 8) = hv;
            }
        }
        __syncthreads();
        #pragma unroll
        for (int p = 0; p < 8; p++) {
            const int n  = p * 16 + (tid >> 5);
            const int gi = tid & 31;
            uint4 v4 = *(const uint4*)((char*)smem + n * 512 +
                                       ((gi ^ (n & 31)) << 4));
            u16* dst = o2 + ((size_t)b * 512 + (N0 - 1024) + n) * 1024 + M0;
            *(uint4*)(dst + gi * 8) = v4;
        }
    }
}

// ---------------------------------------------------------------------------
// 128x128 NT GEMM (r3-proven, used for GEMM2/3/4): BK=64, 256 thr, 4 waves
// (2x2 of 64x64), 32x32x16 MFMA, 4 blocks/CU.  XOR chunk swizzle on LDS.
// C/D layout (m101): col=lane&31, row=(reg&3)+8*(reg>>2)+4*(lane>>5).
// Softmax fold: MODE1 stores P'=exp(s), atomics bf16-rounded row sums into
// rsum (via fo); MODE2 scales by 1/rsum (via xres).
// MODE 1: exp(scores)[b][t=n][s=m] LDS-transpose
// MODE 2: h2[b][t=n][c=m] LDS-transpose
// MODE 3: fp32 out[B,C,T] = acc + bias[n] + x, LDS-transpose
// ---------------------------------------------------------------------------
template <int MODE>
__global__ __launch_bounds__(256, 4) void gemm128(
    const u16* __restrict__ A, const u16* __restrict__ B,
    size_t strideA, size_t strideB, int lda, int ldb, int K,
    u16* __restrict__ o0,
    float* __restrict__ fo, const float* __restrict__ bias,
    const float* __restrict__ xres)
{
    __shared__ __align__(16) u16 sm[16384];   // As | Bs during loop; C-tile after
    u16* As = sm;
    u16* Bs = sm + 8192;

    const int tid   = threadIdx.x;
    const int lane  = tid & 63;
    const int wave  = tid >> 6;
    const int wm    = (wave >> 1) * 64;
    const int wn    = (wave & 1) * 64;
    const int l31   = lane & 31;
    const int khalf = lane >> 5;          // 0,1

    const int gx = gridDim.x, gy = gridDim.y;
    int f = blockIdx.x + gx * (blockIdx.y + gy * blockIdx.z);
    const int nwg = gx * gy * (int)gridDim.z;
    f = (f & 7) * (nwg >> 3) + (f >> 3);
    const int bx  = f % gx;
    const int byz = f / gx;
    const int by  = byz % gy;
    const int b   = byz / gy;

    const u16* Ab = A + (size_t)b * strideA + (size_t)by * 128 * lda;
    const u16* Bb = B + (size_t)b * strideB + (size_t)bx * 128 * ldb;

    const int srow = lane >> 3;
    const int sc   = lane & 7;
    const int scg  = sc ^ srow;

    f32x16 acc[2][2] = {};

    for (int k0 = 0; k0 < K; k0 += 64) {
        __syncthreads();
        #pragma unroll
        for (int s = 0; s < 4; s++) {
            const int r = wave * 32 + s * 8 + srow;
            GLDS16(Ab + (size_t)r * lda + k0 + scg * 8, As + r * 64 + sc * 8);
            GLDS16(Bb + (size_t)r * ldb + k0 + scg * 8, Bs + r * 64 + sc * 8);
        }
        __syncthreads();

        #pragma unroll
        for (int ks = 0; ks < 4; ks++) {
            const int cidx = ks * 2 + khalf;
            const int slot = (cidx ^ (lane & 7)) * 8;
            bf16x8 af[2], bfr[2];
            #pragma unroll
            for (int i = 0; i < 2; i++)
                af[i] = *(const bf16x8*)(As + (wm + i * 32 + l31) * 64 + slot);
            #pragma unroll
            for (int j = 0; j < 2; j++)
                bfr[j] = *(const bf16x8*)(Bs + (wn + j * 32 + l31) * 64 + slot);
            #pragma unroll
            for (int i = 0; i < 2; i++)
                #pragma unroll
                for (int j = 0; j < 2; j++)
                    acc[i][j] = __builtin_amdgcn_mfma_f32_32x32x16_bf16(
                        af[i], bfr[j], acc[i][j], 0, 0, 0);
        }
    }

    const int N0 = bx * 128;
    const int M0 = by * 128;

    if (MODE != 3) {
        // bf16 outputs, rows = n, contiguous m: exp(scores) / h2
        __syncthreads();
        float rinv_[2];
        if (MODE == 2) {
            #pragma unroll
            for (int j = 0; j < 2; j++)
                rinv_[j] = 1.0f / xres[(size_t)b * 1024 + N0 + wn + j * 32 + l31];
        }
        #pragma unroll
        for (int i = 0; i < 2; i++) {
            #pragma unroll
            for (int j = 0; j < 2; j++) {
                const int n = wn + j * 32 + l31;
                #pragma unroll
                for (int g = 0; g < 4; g++) {
                    const int m = wm + 4 * khalf + i * 32 + 8 * g;
                    float a0 = acc[i][j][4 * g],     a1 = acc[i][j][4 * g + 1];
                    float a2 = acc[i][j][4 * g + 2], a3 = acc[i][j][4 * g + 3];
                    if (MODE == 1) {
                        a0 = __expf(a0); a1 = __expf(a1);
                        a2 = __expf(a2); a3 = __expf(a3);
                    }
                    if (MODE == 2) {
                        a0 *= rinv_[j]; a1 *= rinv_[j];
                        a2 *= rinv_[j]; a3 *= rinv_[j];
                    }
                    ushort4 hv = {f2bf(a0), f2bf(a1), f2bf(a2), f2bf(a3)};
                    *(ushort4*)(sm + n * 128 + (((m >> 3) ^ (n & 15)) << 3) + (m & 7)) = hv;
                }
            }
        }
        __syncthreads();
        #pragma unroll
        for (int p = 0; p < 8; p++) {
            const int n  = p * 16 + (tid >> 4);
            const int gi = tid & 15;
            uint4 v = *(const uint4*)(sm + n * 128 + ((gi ^ (n & 15)) << 3));
            u16* dst;
            if (MODE == 1) dst = o0 + ((size_t)b * 1024 + N0 + n) * 1024 + M0;
            else           dst = o0 + ((size_t)b * 1024 + N0 + n) * 512 + M0;
            *(uint4*)(dst + gi * 8) = v;
            if (MODE == 1) {
                unsigned wd_[4] = {v.x, v.y, v.z, v.w};
                float rsm = 0.f;
                #pragma unroll
                for (int q = 0; q < 4; q++)
                    rsm += __builtin_bit_cast(float, wd_[q] << 16)
                         + __builtin_bit_cast(float, wd_[q] & 0xffff0000u);
                #pragma unroll
                for (int off = 1; off < 16; off <<= 1)
                    rsm += __shfl_xor(rsm, off);
                if (gi == 0)
                    atomicAdd(fo + ((size_t)b * 1024 + N0 + n), rsm);
            }
        }
    } else {
        // MODE 3: fp32 out [B,C,T]; two 32KB LDS transpose rounds; +bias +x
        float* smf = (float*)sm;
        #pragma unroll
        for (int i = 0; i < 2; i++) {
            __syncthreads();
            #pragma unroll
            for (int j = 0; j < 2; j++) {
                const int n = wn + j * 32 + l31;
                #pragma unroll
                for (int g = 0; g < 4; g++) {
                    const int mIdx = 4 * khalf + 8 * g + ((wm >> 6) << 5);
                    float4 v4 = {acc[i][j][4 * g],     acc[i][j][4 * g + 1],
                                 acc[i][j][4 * g + 2], acc[i][j][4 * g + 3]};
                    *(float4*)(smf + n * 64 + (((mIdx >> 2) ^ (n & 15)) << 2)) = v4;
                }
            }
            __syncthreads();
            #pragma unroll
            for (int p = 0; p < 8; p++) {
                const int n  = p * 16 + (tid >> 4);
                const int gi = tid & 15;
                float4 v = *(const float4*)(smf + n * 64 + ((gi ^ (n & 15)) << 2));
                const int m = (gi & 7) * 4 + ((gi >> 3) << 6) + 32 * i;
                const size_t off = ((size_t)b * 512 + N0 + n) * 1024 + M0 + m;
                const float bv = bias[N0 + n];
                const float4 xv = *(const float4*)(xres + off);
                float4 ov = {v.x + bv + xv.x, v.y + bv + xv.y,
                             v.z + bv + xv.z, v.w + bv + xv.w};
                *(float4*)(fo + off) = ov;
            }
        }
    }
}

// ---------------------------------------------------------------------------
extern "C" void kernel_launch(void* const* d_in, const int* in_sizes, int n_in,
                              void* d_out, int out_size, void* d_ws, size_t ws_size,
                              hipStream_t stream)
{
    const float* x     = (const float*)d_in[0];
    const float* gamma = (const float*)d_in[1];
    const float* beta  = (const float*)d_in[2];
    const float* Wq    = (const float*)d_in[3];
    const float* bq    = (const float*)d_in[4];
    const float* Wk    = (const float*)d_in[5];
    const float* bk    = (const float*)d_in[6];
    const float* Wv    = (const float*)d_in[7];
    const float* bv    = (const float*)d_in[8];
    const float* Wp    = (const float*)d_in[9];
    const float* bp    = (const float*)d_in[10];

    char* ws = (char*)d_ws;
    u16*   Wqkv   = (u16*)(ws + 0);           //  1,572,864 B
    u16*   Wpb    = (u16*)(ws + 1572864);     //    524,288 B
    float* bqkv   = (float*)(ws + 2097152);   //      8,192 B
    u16*   ht     = (u16*)(ws + 2105344);     // 16,777,216 B (reused as h2)
    u16*   kt     = (u16*)(ws + 18882560);    // 16,777,216 B
    u16*   vv     = (u16*)(ws + 35659776);    // 16,777,216 B
    u16*   scores = (u16*)(ws + 52436992);    // 33,554,432 B bf16 (holds exp(s))
    // total ws: 85,991,424 B
    u16*   qt  = (u16*)d_out;   // scratch: q [B,T,C] bf16 (first 16.8MB)
    float2* stats = (float2*)((char*)d_out + 16777216);  // 4KB scratch
    float* rsum   = (float*)((char*)d_out + 16781312);   // 64KB scratch
    u16*   h2  = ht;
    float* out = (float*)d_out;

    convert_kernel<<<4096, 256, 0, stream>>>(Wq, Wk, Wv, Wp, bq, bk, bv,
                                             Wqkv, Wpb, bqkv, rsum);
    gn_stats<<<dim3(32, 16), 256, 0, stream>>>(x, stats);
    gn_apply<<<dim3(32, 16), 256, 0, stream>>>(x, gamma, beta, stats, ht);

    // GEMM1 qkv (pipelined 256x128): M=1024 N=1536 K=512 ; 768 blocks
    gemm_big<0><<<dim3(12, 4, 16), 512, 0, stream>>>(
        ht, Wqkv, 524288, 0, 512, 512, 512,
        qt, kt, vv, bqkv);

    // GEMM2 scores (128^2, 4/CU): M=1024(S) N=1024(T) K=512 ; 1024 blocks
    // writes P' = exp(s) and accumulates rsum[b][t]
    gemm128<1><<<dim3(8, 8, 16), 256, 0, stream>>>(
        kt, qt, 524288, 524288, 512, 512, 512,
        scores, rsum, nullptr, nullptr);

    // GEMM3 pv (128^2): M=512(C) N=1024(T) K=1024(S) ; 512 blocks
    gemm128<2><<<dim3(8, 4, 16), 256, 0, stream>>>(
        vv, scores, 524288, 1048576, 1024, 1024, 1024,
        h2, nullptr, nullptr, rsum);

    // GEMM4 proj+residual (128^2): M=1024(T) N=512(C) K=512 ; 512 blocks
    gemm128<3><<<dim3(4, 8, 16), 256, 0, stream>>>(
        h2, Wpb, 524288, 0, 512, 512, 512,
        nullptr, out, bp, x);
}

// Round 9
// 221.377 us; speedup vs baseline: 1.1310x; 1.0258x over previous
//
#include <hip/hip_runtime.h>

typedef unsigned short u16;
typedef __bf16 bf16x8 __attribute__((ext_vector_type(8)));
typedef float f32x4 __attribute__((ext_vector_type(4)));

__device__ __forceinline__ u16 f2bf(float f) {
    unsigned u = __builtin_bit_cast(unsigned, f);
    u += 0x7fffu + ((u >> 16) & 1u);
    return (u16)(u >> 16);
}
__device__ __forceinline__ float bf2f(u16 h) {
    return __builtin_bit_cast(float, (unsigned)h << 16);
}

#define GLDS16(g, l) __builtin_amdgcn_global_load_lds( \
    (const __attribute__((address_space(1))) void*)(g), \
    (__attribute__((address_space(3))) void*)(l), 16, 0, 0)

#define QK_SCALE 0.044194173824159216f

// ---------------------------------------------------------------------------
// Fused preamble: weight conversion + rsum zero-init (blocks 0..4095) and
// GroupNorm stats (blocks 4096..4607; one per (b,g)).  Disjoint work, one
// launch instead of two.
// ---------------------------------------------------------------------------
__global__ __launch_bounds__(256) void fused_pre(
    const float* __restrict__ Wq, const float* __restrict__ Wk,
    const float* __restrict__ Wv, const float* __restrict__ Wp,
    const float* __restrict__ bq, const float* __restrict__ bk,
    const float* __restrict__ bv,
    u16* __restrict__ Wqkv, u16* __restrict__ Wpb, float* __restrict__ bqkv,
    float* __restrict__ rsum,
    const float* __restrict__ x, float2* __restrict__ stats)
{
    __shared__ float rs[4], rs2[4];
    const int tid = threadIdx.x;

    if (blockIdx.x < 4096) {
        int idx = blockIdx.x * 256 + tid;
        if (idx < 786432) {
            int which = idx >> 18;
            int off   = idx & 262143;
            if (which == 0)
                Wqkv[idx] = f2bf(Wq[off] * QK_SCALE);
            else
                Wqkv[idx] = f2bf(((which == 1) ? Wk : Wv)[off]);
        } else {
            int off = idx - 786432;
            Wpb[off] = f2bf(Wp[off]);
        }
        if (idx < 1536) {
            float bvv = (idx < 512) ? bq[idx] * QK_SCALE
                      : (idx < 1024) ? bk[idx & 511] : bv[idx & 511];
            bqkv[idx] = bvv;
        }
        if (idx < 16384) rsum[idx] = 0.f;
        return;
    }

    // ---- GroupNorm stats ----
    const int rem = blockIdx.x - 4096;
    const int g = rem & 31, b = rem >> 5;
    const float* xg = x + ((size_t)b * 512 + (size_t)g * 16) * 1024;

    float s = 0.f, s2 = 0.f;
    const float4* x4 = (const float4*)xg;
    #pragma unroll 4
    for (int i = tid; i < 4096; i += 256) {
        float4 v = x4[i];
        s  += v.x + v.y + v.z + v.w;
        s2 += v.x * v.x + v.y * v.y + v.z * v.z + v.w * v.w;
    }
    #pragma unroll
    for (int off = 32; off; off >>= 1) {
        s  += __shfl_down(s, off);
        s2 += __shfl_down(s2, off);
    }
    const int w = tid >> 6;
    if ((tid & 63) == 0) { rs[w] = s; rs2[w] = s2; }
    __syncthreads();
    if (tid == 0) {
        float S  = rs[0] + rs[1] + rs[2] + rs[3];
        float S2 = rs2[0] + rs2[1] + rs2[2] + rs2[3];
        float mean = S * (1.f / 16384.f);
        float var  = S2 * (1.f / 16384.f) - mean * mean;
        stats[b * 32 + g] = make_float2(mean, rsqrtf(var + 1e-5f));
    }
}

// ---------------------------------------------------------------------------
// GroupNorm apply + transpose: x [B,C,T] fp32 -> ht [B,T,C] bf16.
// ---------------------------------------------------------------------------
__global__ __launch_bounds__(256) void gn_apply(
    const float* __restrict__ x, const float* __restrict__ gamma,
    const float* __restrict__ beta, const float2* __restrict__ stats,
    u16* __restrict__ ht)
{
    const int tc = blockIdx.x, b = blockIdx.y, tid = threadIdx.x;
    const int t0 = tc * 32;

    __shared__ float2 st[32];
    __shared__ float ga[512], be[512];
    __shared__ __align__(16) u16 tile[512 * 32];

    if (tid < 32) st[tid] = stats[b * 32 + tid];
    for (int c = tid; c < 512; c += 256) { ga[c] = gamma[c]; be[c] = beta[c]; }
    __syncthreads();

    #pragma unroll
    for (int pass = 0; pass < 16; pass++) {
        const int c = pass * 32 + (tid >> 3);
        const int f = tid & 7;
        float4 v = *(const float4*)(x + ((size_t)(b * 512 + c)) * 1024 + t0 + f * 4);
        float2 s = st[c >> 4];
        float sc = s.y * ga[c];
        float sh = be[c] - s.x * sc;
        ushort4 hv = {f2bf(v.x * sc + sh), f2bf(v.y * sc + sh),
                      f2bf(v.z * sc + sh), f2bf(v.w * sc + sh)};
        const int slot = f ^ (c & 7) ^ ((c >> 3) & 7);
        *(ushort4*)(tile + c * 32 + slot * 4) = hv;
    }
    __syncthreads();

    #pragma unroll
    for (int p = 0; p < 8; p++) {
        const int t = p * 4 + (tid >> 6);
        const int l = tid & 63;
        u16 tmp[8];
        #pragma unroll
        for (int e = 0; e < 8; e++) {
            const int c = l * 8 + e;
            const int slot = (t >> 2) ^ (c & 7) ^ ((c >> 3) & 7);
            tmp[e] = tile[c * 32 + slot * 4 + (t & 3)];
        }
        *(uint4*)(ht + ((size_t)b * 1024 + t0 + t) * 512 + l * 8) = *(uint4*)tmp;
    }
}

// ---------------------------------------------------------------------------
// Pipelined NT GEMM (r4-proven, GEMM1 only): BM=256 BN=128 BK=64, 8 waves,
// 3 LDS bufs, counted vmcnt(6), 1 barrier/K-tile, 2 ks-phases, setprio.
// MODE 0: qkv (q,k [B,T,C] direct; v [B,C,T] LDS-transpose) + bias.
// ---------------------------------------------------------------------------
template <int MODE>
__global__ __launch_bounds__(512, 2) void gemm_big(
    const u16* __restrict__ A, const u16* __restrict__ B,
    size_t strideA, size_t strideB, int lda, int ldb, int K,
    u16* __restrict__ o0, u16* __restrict__ o1, u16* __restrict__ o2,
    const float* __restrict__ bias)
{
    __shared__ __align__(16) u16 smem[73728];   // 144 KB
    u16* As = smem;                  // 3 x 16384 elems (256x64)
    u16* Bs = smem + 49152;          // 3 x  8192 elems (128x64)

    const int tid  = threadIdx.x;
    const int lane = tid & 63;
    const int wave = tid >> 6;
    const int wm   = (wave & 3) * 64;
    const int wn   = (wave >> 2) * 64;

    const int gx = gridDim.x, gy = gridDim.y;
    int f = blockIdx.x + gx * (blockIdx.y + gy * blockIdx.z);
    const int nwg = gx * gy * (int)gridDim.z;
    f = (f & 7) * (nwg >> 3) + (f >> 3);
    const int bx  = f % gx;
    const int byz = f / gx;
    const int by  = byz % gy;
    const int b   = byz / gy;

    const u16* Ab = A + (size_t)b * strideA + (size_t)by * 256 * lda;
    const u16* Bb = B + (size_t)b * strideB + (size_t)bx * 128 * ldb;

    const int srow = tid >> 3;
    const int sc   = tid & 7;
    const int scg  = sc ^ (srow & 7);

    const u16* aSrc[4]; int aDst[4];
    #pragma unroll
    for (int u = 0; u < 4; u++) {
        aSrc[u] = Ab + (size_t)(u * 64 + srow) * lda + scg * 8;
        aDst[u] = (u * 64 + srow) * 64 + sc * 8;
    }
    const u16* bSrc[2]; int bDst[2];
    #pragma unroll
    for (int u = 0; u < 2; u++) {
        bSrc[u] = Bb + (size_t)(u * 64 + srow) * ldb + scg * 8;
        bDst[u] = (u * 64 + srow) * 64 + sc * 8;
    }

    const int l15 = lane & 15, lh = lane >> 4, rx = lane & 7;
    int aOff[4][2], bOff[4][2];
    #pragma unroll
    for (int i = 0; i < 4; i++)
        #pragma unroll
        for (int ks = 0; ks < 2; ks++) {
            const int slot = ((ks << 2) + lh) ^ rx;
            aOff[i][ks] = (wm + i * 16 + l15) * 64 + slot * 8;
            bOff[i][ks] = (wn + i * 16 + l15) * 64 + slot * 8;
        }

    f32x4 acc[4][4] = {};
    const int NT = K >> 6;

    #pragma unroll
    for (int u = 0; u < 4; u++) GLDS16(aSrc[u], As + aDst[u]);
    #pragma unroll
    for (int u = 0; u < 2; u++) GLDS16(bSrc[u], Bs + bDst[u]);
    #pragma unroll
    for (int u = 0; u < 4; u++) GLDS16(aSrc[u] + 64, As + 16384 + aDst[u]);
    #pragma unroll
    for (int u = 0; u < 2; u++) GLDS16(bSrc[u] + 64, Bs + 8192 + bDst[u]);

    int cbuf = 0, sbuf = 2;
    for (int t = 0; t < NT; ++t) {
        if (t == NT - 1) asm volatile("s_waitcnt vmcnt(0)" ::: "memory");
        else             asm volatile("s_waitcnt vmcnt(6)" ::: "memory");
        __builtin_amdgcn_s_barrier();

        const u16* Ac = As + cbuf * 16384;
        const u16* Bc = Bs + cbuf * 8192;
        u16* Asb = As + sbuf * 16384;
        u16* Bsb = Bs + sbuf * 8192;
        const int ko = (t + 2) * 64;
        const bool pf = (t + 2 < NT);

        if (pf) {
            GLDS16(aSrc[0] + ko, Asb + aDst[0]);
            GLDS16(aSrc[1] + ko, Asb + aDst[1]);
            GLDS16(bSrc[0] + ko, Bsb + bDst[0]);
        }
        {
            bf16x8 af[4], bfr[4];
            #pragma unroll
            for (int i = 0; i < 4; i++) {
                af[i]  = *(const bf16x8*)(Ac + aOff[i][0]);
                bfr[i] = *(const bf16x8*)(Bc + bOff[i][0]);
            }
            __builtin_amdgcn_s_setprio(1);
            #pragma unroll
            for (int mi = 0; mi < 4; mi++)
                #pragma unroll
                for (int nj = 0; nj < 4; nj++)
                    acc[mi][nj] = __builtin_amdgcn_mfma_f32_16x16x32_bf16(
                        af[mi], bfr[nj], acc[mi][nj], 0, 0, 0);
            __builtin_amdgcn_s_setprio(0);
        }
        if (pf) {
            GLDS16(aSrc[2] + ko, Asb + aDst[2]);
            GLDS16(aSrc[3] + ko, Asb + aDst[3]);
            GLDS16(bSrc[1] + ko, Bsb + bDst[1]);
        }
        {
            bf16x8 af[4], bfr[4];
            #pragma unroll
            for (int i = 0; i < 4; i++) {
                af[i]  = *(const bf16x8*)(Ac + aOff[i][1]);
                bfr[i] = *(const bf16x8*)(Bc + bOff[i][1]);
            }
            __builtin_amdgcn_s_setprio(1);
            #pragma unroll
            for (int mi = 0; mi < 4; mi++)
                #pragma unroll
                for (int nj = 0; nj < 4; nj++)
                    acc[mi][nj] = __builtin_amdgcn_mfma_f32_16x16x32_bf16(
                        af[mi], bfr[nj], acc[mi][nj], 0, 0, 0);
            __builtin_amdgcn_s_setprio(0);
        }

        cbuf = (cbuf == 2) ? 0 : cbuf + 1;
        sbuf = (sbuf == 2) ? 0 : sbuf + 1;
    }

    const int N0 = bx * 128;
    const int M0 = by * 256;

    if (N0 < 1024) {
        // q or k: [B,T,C] direct scalar stores; block covers full 128-n span
        u16* dst = (N0 < 512) ? o0 : o1;
        const int nn0 = N0 & 511;
        #pragma unroll
        for (int nj = 0; nj < 4; nj++) {
            const int n = wn + nj * 16 + l15;
            const float bv = bias[N0 + n];
            #pragma unroll
            for (int mi = 0; mi < 4; mi++) {
                const int mq = M0 + wm + mi * 16 + lh * 4;
                const size_t base = ((size_t)b * 1024 + mq) * 512 + nn0 + n;
                dst[base]        = f2bf(acc[mi][nj][0] + bv);
                dst[base + 512]  = f2bf(acc[mi][nj][1] + bv);
                dst[base + 1024] = f2bf(acc[mi][nj][2] + bv);
                dst[base + 1536] = f2bf(acc[mi][nj][3] + bv);
            }
        }
    } else {
        // v: [B,C,T] via LDS transpose, 512B-row coalesced stores
        __syncthreads();
        #pragma unroll
        for (int mi = 0; mi < 4; mi++) {
            const int mq = wm + mi * 16 + lh * 4;
            #pragma unroll
            for (int nj = 0; nj < 4; nj++) {
                const int n = wn + nj * 16 + l15;
                const float bv = bias[N0 + n];
                ushort4 hv = {f2bf(acc[mi][nj][0] + bv), f2bf(acc[mi][nj][1] + bv),
                              f2bf(acc[mi][nj][2] + bv), f2bf(acc[mi][nj][3] + bv)};
                *(ushort4*)((char*)smem + n * 512 +
                            (((mq >> 3) ^ (n & 31)) << 4) + ((mq >> 2) & 1) * 8) = hv;
            }
        }
        __syncthreads();
        #pragma unroll
        for (int p = 0; p < 8; p++) {
            const int n  = p * 16 + (tid >> 5);
            const int gi = tid & 31;
            uint4 v4 = *(const uint4*)((char*)smem + n * 512 +
                                       ((gi ^ (n & 31)) << 4));
            u16* dst = o2 + ((size_t)b * 512 + (N0 - 1024) + n) * 1024 + M0;
            *(uint4*)(dst + gi * 8) = v4;
        }
    }
}

// ---------------------------------------------------------------------------
// 128x128 NT GEMM for GEMM2/3/4 — r9: inner loop ported to the gemm_big
// fragment pattern (16x16x32 MFMA, 16-row frags) which measures 131K LDS
// bank-conflict cycles vs 3.28M for the old 32-row (32x32x16) pattern.
// Staging, tile, grids, occupancy (4 blocks/CU) unchanged.
// C/D layout (m89): col=lane&15, row=(lane>>4)*4+reg.
// MODE 1: exp(scores)[b][t=n][s=m] LDS-transpose (+rsum atomics via fo)
// MODE 2: h2[b][t=n][c=m] LDS-transpose (1/rsum scale via xres)
// MODE 3: fp32 out[B,C,T] = acc + bias[n] + x, 2-round LDS-transpose
// ---------------------------------------------------------------------------
template <int MODE>
__global__ __launch_bounds__(256, 4) void gemm128(
    const u16* __restrict__ A, const u16* __restrict__ B,
    size_t strideA, size_t strideB, int lda, int ldb, int K,
    u16* __restrict__ o0,
    float* __restrict__ fo, const float* __restrict__ bias,
    const float* __restrict__ xres)
{
    __shared__ __align__(16) u16 sm[16384];   // As | Bs during loop; C-tile after
    u16* As = sm;
    u16* Bs = sm + 8192;

    const int tid  = threadIdx.x;
    const int lane = tid & 63;
    const int wave = tid >> 6;
    const int wm   = (wave >> 1) * 64;
    const int wn   = (wave & 1) * 64;
    const int l15  = lane & 15;
    const int lh   = lane >> 4;
    const int rx   = lane & 7;

    const int gx = gridDim.x, gy = gridDim.y;
    int f = blockIdx.x + gx * (blockIdx.y + gy * blockIdx.z);
    const int nwg = gx * gy * (int)gridDim.z;
    f = (f & 7) * (nwg >> 3) + (f >> 3);
    const int bx  = f % gx;
    const int byz = f / gx;
    const int by  = byz % gy;
    const int b   = byz / gy;

    const u16* Ab = A + (size_t)b * strideA + (size_t)by * 128 * lda;
    const u16* Bb = B + (size_t)b * strideB + (size_t)bx * 128 * ldb;

    const int srow = lane >> 3;           // 0..7
    const int sc   = lane & 7;
    const int scg  = sc ^ srow;           // LDS[row][slot] holds granule slot^(row&7)

    // frag read offsets: row = base + i*16 + l15 (row&7 == rx), granule (ks*4+lh)
    int aOff[4][2], bOff[4][2];
    #pragma unroll
    for (int i = 0; i < 4; i++)
        #pragma unroll
        for (int ks = 0; ks < 2; ks++) {
            const int slot = ((ks << 2) + lh) ^ rx;
            aOff[i][ks] = (wm + i * 16 + l15) * 64 + slot * 8;
            bOff[i][ks] = (wn + i * 16 + l15) * 64 + slot * 8;
        }

    f32x4 acc[4][4] = {};

    for (int k0 = 0; k0 < K; k0 += 64) {
        __syncthreads();
        #pragma unroll
        for (int s = 0; s < 4; s++) {
            const int r = wave * 32 + s * 8 + srow;
            GLDS16(Ab + (size_t)r * lda + k0 + scg * 8, As + r * 64 + sc * 8);
            GLDS16(Bb + (size_t)r * ldb + k0 + scg * 8, Bs + r * 64 + sc * 8);
        }
        __syncthreads();

        #pragma unroll
        for (int ks = 0; ks < 2; ks++) {
            bf16x8 af[4], bfr[4];
            #pragma unroll
            for (int i = 0; i < 4; i++) {
                af[i]  = *(const bf16x8*)(As + aOff[i][ks]);
                bfr[i] = *(const bf16x8*)(Bs + bOff[i][ks]);
            }
            __builtin_amdgcn_s_setprio(1);
            #pragma unroll
            for (int mi = 0; mi < 4; mi++)
                #pragma unroll
                for (int nj = 0; nj < 4; nj++)
                    acc[mi][nj] = __builtin_amdgcn_mfma_f32_16x16x32_bf16(
                        af[mi], bfr[nj], acc[mi][nj], 0, 0, 0);
            __builtin_amdgcn_s_setprio(0);
        }
    }

    const int N0 = bx * 128;
    const int M0 = by * 128;

    if (MODE != 3) {
        // stage bf16 C-tile [n:128][m:128] (32 KB), 16B-granule XOR swizzle
        __syncthreads();
        float rinv_[4];
        if (MODE == 2) {
            #pragma unroll
            for (int nj = 0; nj < 4; nj++)
                rinv_[nj] = 1.0f / xres[(size_t)b * 1024 + N0 + wn + nj * 16 + l15];
        }
        #pragma unroll
        for (int mi = 0; mi < 4; mi++) {
            const int mq  = wm + mi * 16 + lh * 4;      // multiple of 4
            const int gsl = mq >> 3;
            const int gb  = ((mq >> 2) & 1) * 8;
            #pragma unroll
            for (int nj = 0; nj < 4; nj++) {
                const int n = wn + nj * 16 + l15;
                float a0 = acc[mi][nj][0], a1 = acc[mi][nj][1];
                float a2 = acc[mi][nj][2], a3 = acc[mi][nj][3];
                if (MODE == 1) {
                    a0 = __expf(a0); a1 = __expf(a1);
                    a2 = __expf(a2); a3 = __expf(a3);
                }
                if (MODE == 2) {
                    a0 *= rinv_[nj]; a1 *= rinv_[nj];
                    a2 *= rinv_[nj]; a3 *= rinv_[nj];
                }
                ushort4 hv = {f2bf(a0), f2bf(a1), f2bf(a2), f2bf(a3)};
                *(ushort4*)((char*)sm + n * 256 +
                            ((gsl ^ (n & 15)) << 4) + gb) = hv;
            }
        }
        __syncthreads();
        #pragma unroll
        for (int p = 0; p < 8; p++) {
            const int n  = p * 16 + (tid >> 4);
            const int gi = tid & 15;
            uint4 v = *(const uint4*)((char*)sm + n * 256 + ((gi ^ (n & 15)) << 4));
            u16* dst;
            if (MODE == 1) dst = o0 + ((size_t)b * 1024 + N0 + n) * 1024 + M0;
            else           dst = o0 + ((size_t)b * 1024 + N0 + n) * 512 + M0;
            *(uint4*)(dst + gi * 8) = v;
            if (MODE == 1) {
                unsigned wd_[4] = {v.x, v.y, v.z, v.w};
                float rsm = 0.f;
                #pragma unroll
                for (int q = 0; q < 4; q++)
                    rsm += __builtin_bit_cast(float, wd_[q] << 16)
                         + __builtin_bit_cast(float, wd_[q] & 0xffff0000u);
                #pragma unroll
                for (int off = 1; off < 16; off <<= 1)
                    rsm += __shfl_xor(rsm, off);
                if (gi == 0)
                    atomicAdd(fo + ((size_t)b * 1024 + N0 + n), rsm);
            }
        }
    } else {
        // MODE 3: fp32 [n:128][m-half:64] tile (32 KB), two rounds by m-half;
        // waves with wm == half*64 stage, then all gather+store +bias +x.
        float* smf = (float*)sm;
        #pragma unroll
        for (int half = 0; half < 2; half++) {
            __syncthreads();
            if ((wave >> 1) == half) {
                #pragma unroll
                for (int mi = 0; mi < 4; mi++) {
                    const int mloc = mi * 16 + lh * 4;      // 0..63, mult of 4
                    const int gsl  = mloc >> 2;             // 16B granule 0..15
                    #pragma unroll
                    for (int nj = 0; nj < 4; nj++) {
                        const int n = wn + nj * 16 + l15;
                        float4 v4 = {acc[mi][nj][0], acc[mi][nj][1],
                                     acc[mi][nj][2], acc[mi][nj][3]};
                        *(float4*)((char*)smf + n * 256 +
                                   ((gsl ^ (n & 15)) << 4)) = v4;
                    }
                }
            }
            __syncthreads();
            #pragma unroll
            for (int p = 0; p < 8; p++) {
                const int n  = p * 16 + (tid >> 4);
                const int gi = tid & 15;
                float4 v = *(const float4*)((char*)smf + n * 256 +
                                            ((gi ^ (n & 15)) << 4));
                const int m = half * 64 + gi * 4;
                const size_t off = ((size_t)b * 512 + N0 + n) * 1024 + M0 + m;
                const float bv = bias[N0 + n];
                const float4 xv = *(const float4*)(xres + off);
                float4 ov = {v.x + bv + xv.x, v.y + bv + xv.y,
                             v.z + bv + xv.z, v.w + bv + xv.w};
                *(float4*)(fo + off) = ov;
            }
        }
    }
}

// ---------------------------------------------------------------------------
extern "C" void kernel_launch(void* const* d_in, const int* in_sizes, int n_in,
                              void* d_out, int out_size, void* d_ws, size_t ws_size,
                              hipStream_t stream)
{
    const float* x     = (const float*)d_in[0];
    const float* gamma = (const float*)d_in[1];
    const float* beta  = (const float*)d_in[2];
    const float* Wq    = (const float*)d_in[3];
    const float* bq    = (const float*)d_in[4];
    const float* Wk    = (const float*)d_in[5];
    const float* bk    = (const float*)d_in[6];
    const float* Wv    = (const float*)d_in[7];
    const float* bv    = (const float*)d_in[8];
    const float* Wp    = (const float*)d_in[9];
    const float* bp    = (const float*)d_in[10];

    char* ws = (char*)d_ws;
    u16*   Wqkv   = (u16*)(ws + 0);           //  1,572,864 B
    u16*   Wpb    = (u16*)(ws + 1572864);     //    524,288 B
    float* bqkv   = (float*)(ws + 2097152);   //      8,192 B
    u16*   ht     = (u16*)(ws + 2105344);     // 16,777,216 B (reused as h2)
    u16*   kt     = (u16*)(ws + 18882560);    // 16,777,216 B
    u16*   vv     = (u16*)(ws + 35659776);    // 16,777,216 B
    u16*   scores = (u16*)(ws + 52436992);    // 33,554,432 B bf16 (holds exp(s))
    // total ws: 85,991,424 B
    u16*   qt  = (u16*)d_out;   // scratch: q [B,T,C] bf16 (first 16.8MB)
    float2* stats = (float2*)((char*)d_out + 16777216);  // 4KB scratch
    float* rsum   = (float*)((char*)d_out + 16781312);   // 64KB scratch
    u16*   h2  = ht;
    float* out = (float*)d_out;

    // convert + rsum-init + gn_stats in one launch
    fused_pre<<<4608, 256, 0, stream>>>(Wq, Wk, Wv, Wp, bq, bk, bv,
                                        Wqkv, Wpb, bqkv, rsum, x, stats);
    gn_apply<<<dim3(32, 16), 256, 0, stream>>>(x, gamma, beta, stats, ht);

    // GEMM1 qkv (pipelined 256x128): M=1024 N=1536 K=512 ; 768 blocks
    gemm_big<0><<<dim3(12, 4, 16), 512, 0, stream>>>(
        ht, Wqkv, 524288, 0, 512, 512, 512,
        qt, kt, vv, bqkv);

    // GEMM2 scores (128^2, 4/CU): M=1024(S) N=1024(T) K=512 ; 1024 blocks
    // writes P' = exp(s) and accumulates rsum[b][t]
    gemm128<1><<<dim3(8, 8, 16), 256, 0, stream>>>(
        kt, qt, 524288, 524288, 512, 512, 512,
        scores, rsum, nullptr, nullptr);

    // GEMM3 pv (128^2): M=512(C) N=1024(T) K=1024(S) ; 512 blocks
    gemm128<2><<<dim3(8, 4, 16), 256, 0, stream>>>(
        vv, scores, 524288, 1048576, 1024, 1024, 1024,
        h2, nullptr, nullptr, rsum);

    // GEMM4 proj+residual (128^2): M=1024(T) N=512(C) K=512 ; 512 blocks
    gemm128<3><<<dim3(4, 8, 16), 256, 0, stream>>>(
        h2, Wpb, 524288, 0, 512, 512, 512,
        nullptr, out, bp, x);
}

// Round 11
// 214.867 us; speedup vs baseline: 1.1652x; 1.0303x over previous
//
#include <hip/hip_runtime.h>

typedef unsigned short u16;
typedef __bf16 bf16x8 __attribute__((ext_vector_type(8)));
typedef float f32x4 __attribute__((ext_vector_type(4)));

__device__ __forceinline__ u16 f2bf(float f) {
    unsigned u = __builtin_bit_cast(unsigned, f);
    u += 0x7fffu + ((u >> 16) & 1u);
    return (u16)(u >> 16);
}
__device__ __forceinline__ float bf2f(u16 h) {
    return __builtin_bit_cast(float, (unsigned)h << 16);
}

#define GLDS16(g, l) __builtin_amdgcn_global_load_lds( \
    (const __attribute__((address_space(1))) void*)(g), \
    (__attribute__((address_space(3))) void*)(l), 16, 0, 0)

#define QK_SCALE 0.044194173824159216f

// ---------------------------------------------------------------------------
// Fused preamble v2 (ONE kernel, 512 blocks = one per (b, group)):
//   * weight convert fp32->bf16 (8 elems/thread, disjoint ride-along)
//   * bqkv concat + rsum zero-init
//   * GroupNorm single-pass: LDS-cache the (b,g) 16c x 1024t slice (64 KB),
//     stats from registers during load, normalize from LDS, write ht.
// x is read ONCE (was twice: stats pass + apply pass); one launch fewer.
// ht write = 32B/t segments (L2 RMW ~17MB accepted, < the 67MB read saved).
// ---------------------------------------------------------------------------
__global__ __launch_bounds__(256) void gn_fused(
    const float* __restrict__ Wq, const float* __restrict__ Wk,
    const float* __restrict__ Wv, const float* __restrict__ Wp,
    const float* __restrict__ bq, const float* __restrict__ bk,
    const float* __restrict__ bv,
    const float* __restrict__ x, const float* __restrict__ gamma,
    const float* __restrict__ beta,
    u16* __restrict__ Wqkv, u16* __restrict__ Wpb, float* __restrict__ bqkv,
    float* __restrict__ rsum, u16* __restrict__ ht)
{
    __shared__ float xs[16 * 1024];          // 64 KB slice [c:16][t:1024]
    __shared__ float rs[4], rs2[4], stat2[2];

    const int tid  = threadIdx.x;
    const int blk  = blockIdx.x;             // 0..511
    const int gidx = blk * 256 + tid;        // 0..131071

    // ---- weight convert: 8 consecutive elems per thread (exact cover) ----
    {
        const int base  = gidx * 8;          // 0..1048568; boundaries % 8 == 0
        const int which = base >> 18;        // 0:Wq 1:Wk 2:Wv 3:Wp
        const int off   = base & 262143;
        const float* src = (which == 0) ? Wq + off
                         : (which == 1) ? Wk + off
                         : (which == 2) ? Wv + off : Wp + off;
        const float sc = (which == 0) ? QK_SCALE : 1.0f;
        float4 a = ((const float4*)src)[0];
        float4 c = ((const float4*)src)[1];
        u16 h[8] = {f2bf(a.x * sc), f2bf(a.y * sc), f2bf(a.z * sc), f2bf(a.w * sc),
                    f2bf(c.x * sc), f2bf(c.y * sc), f2bf(c.z * sc), f2bf(c.w * sc)};
        if (which < 3) *(uint4*)(Wqkv + base) = *(uint4*)h;
        else           *(uint4*)(Wpb + (base - 786432)) = *(uint4*)h;
    }
    if (gidx < 1536) {
        bqkv[gidx] = (gidx < 512) ? bq[gidx] * QK_SCALE
                   : (gidx < 1024) ? bk[gidx & 511] : bv[gidx & 511];
    }
    if (gidx < 16384) rsum[gidx] = 0.f;

    // ---- GN: load slice to LDS, accumulate stats in-flight ----
    const int b = blk >> 5, g = blk & 31;
    const float4* xg4 = (const float4*)(x + ((size_t)b * 512 + (size_t)g * 16) * 1024);
    float4* xs4 = (float4*)xs;
    float s = 0.f, s2 = 0.f;
    #pragma unroll
    for (int i = 0; i < 16; i++) {
        float4 v = xg4[i * 256 + tid];
        xs4[i * 256 + tid] = v;
        s  += v.x + v.y + v.z + v.w;
        s2 += v.x * v.x + v.y * v.y + v.z * v.z + v.w * v.w;
    }
    #pragma unroll
    for (int off = 32; off; off >>= 1) {
        s  += __shfl_down(s, off);
        s2 += __shfl_down(s2, off);
    }
    const int w = tid >> 6;
    if ((tid & 63) == 0) { rs[w] = s; rs2[w] = s2; }
    __syncthreads();
    if (tid == 0) {
        float S  = rs[0] + rs[1] + rs[2] + rs[3];
        float S2 = rs2[0] + rs2[1] + rs2[2] + rs2[3];
        float mean = S * (1.f / 16384.f);
        float var  = S2 * (1.f / 16384.f) - mean * mean;
        stat2[0] = mean;
        stat2[1] = rsqrtf(var + 1e-5f);
    }
    __syncthreads();
    const float mean = stat2[0], rstd = stat2[1];

    float scl[16], shf[16];
    #pragma unroll
    for (int c = 0; c < 16; c++) {
        float ga = gamma[g * 16 + c];
        scl[c] = rstd * ga;
        shf[c] = beta[g * 16 + c] - mean * scl[c];
    }

    // ---- apply from LDS + write ht[b][t][g*16..+16) (32B per t) ----
    // LDS read xs[c*1024 + t]: per instruction c fixed, lanes span t ->
    // consecutive banks, conflict-free.
    #pragma unroll
    for (int i = 0; i < 4; i++) {
        const int t = i * 256 + tid;
        u16 h[16];
        #pragma unroll
        for (int c = 0; c < 16; c++)
            h[c] = f2bf(xs[c * 1024 + t] * scl[c] + shf[c]);
        uint4* d = (uint4*)(ht + ((size_t)b * 1024 + t) * 512 + g * 16);
        d[0] = ((uint4*)h)[0];
        d[1] = ((uint4*)h)[1];
    }
}

// ---------------------------------------------------------------------------
// Pipelined NT GEMM (r4-proven): BM=256 BN=128 BK=64, 8 waves, 3 LDS bufs,
// counted vmcnt(6), 1 barrier/K-tile, 2 ks-phases, setprio around MFMA.
// MODE 0: qkv (q,k [B,T,C] direct; v [B,C,T] LDS-transpose) + bias.
// MODE 1: exp(scores)[b][t=n][s=m] LDS-transpose + rsum atomics (via fo).
// ---------------------------------------------------------------------------
template <int MODE>
__global__ __launch_bounds__(512, 2) void gemm_big(
    const u16* __restrict__ A, const u16* __restrict__ B,
    size_t strideA, size_t strideB, int lda, int ldb, int K,
    u16* __restrict__ o0, u16* __restrict__ o1, u16* __restrict__ o2,
    float* __restrict__ fo, const float* __restrict__ bias)
{
    __shared__ __align__(16) u16 smem[73728];   // 144 KB
    u16* As = smem;                  // 3 x 16384 elems (256x64)
    u16* Bs = smem + 49152;          // 3 x  8192 elems (128x64)

    const int tid  = threadIdx.x;
    const int lane = tid & 63;
    const int wave = tid >> 6;
    const int wm   = (wave & 3) * 64;
    const int wn   = (wave >> 2) * 64;

    const int gx = gridDim.x, gy = gridDim.y;
    int f = blockIdx.x + gx * (blockIdx.y + gy * blockIdx.z);
    const int nwg = gx * gy * (int)gridDim.z;
    f = (f & 7) * (nwg >> 3) + (f >> 3);
    const int bx  = f % gx;
    const int byz = f / gx;
    const int by  = byz % gy;
    const int b   = byz / gy;

    const u16* Ab = A + (size_t)b * strideA + (size_t)by * 256 * lda;
    const u16* Bb = B + (size_t)b * strideB + (size_t)bx * 128 * ldb;

    const int srow = tid >> 3;
    const int sc   = tid & 7;
    const int scg  = sc ^ (srow & 7);

    const u16* aSrc[4]; int aDst[4];
    #pragma unroll
    for (int u = 0; u < 4; u++) {
        aSrc[u] = Ab + (size_t)(u * 64 + srow) * lda + scg * 8;
        aDst[u] = (u * 64 + srow) * 64 + sc * 8;
    }
    const u16* bSrc[2]; int bDst[2];
    #pragma unroll
    for (int u = 0; u < 2; u++) {
        bSrc[u] = Bb + (size_t)(u * 64 + srow) * ldb + scg * 8;
        bDst[u] = (u * 64 + srow) * 64 + sc * 8;
    }

    const int l15 = lane & 15, lh = lane >> 4, rx = lane & 7;
    int aOff[4][2], bOff[4][2];
    #pragma unroll
    for (int i = 0; i < 4; i++)
        #pragma unroll
        for (int ks = 0; ks < 2; ks++) {
            const int slot = ((ks << 2) + lh) ^ rx;
            aOff[i][ks] = (wm + i * 16 + l15) * 64 + slot * 8;
            bOff[i][ks] = (wn + i * 16 + l15) * 64 + slot * 8;
        }

    f32x4 acc[4][4] = {};
    const int NT = K >> 6;

    #pragma unroll
    for (int u = 0; u < 4; u++) GLDS16(aSrc[u], As + aDst[u]);
    #pragma unroll
    for (int u = 0; u < 2; u++) GLDS16(bSrc[u], Bs + bDst[u]);
    #pragma unroll
    for (int u = 0; u < 4; u++) GLDS16(aSrc[u] + 64, As + 16384 + aDst[u]);
    #pragma unroll
    for (int u = 0; u < 2; u++) GLDS16(bSrc[u] + 64, Bs + 8192 + bDst[u]);

    int cbuf = 0, sbuf = 2;
    for (int t = 0; t < NT; ++t) {
        if (t == NT - 1) asm volatile("s_waitcnt vmcnt(0)" ::: "memory");
        else             asm volatile("s_waitcnt vmcnt(6)" ::: "memory");
        __builtin_amdgcn_s_barrier();

        const u16* Ac = As + cbuf * 16384;
        const u16* Bc = Bs + cbuf * 8192;
        u16* Asb = As + sbuf * 16384;
        u16* Bsb = Bs + sbuf * 8192;
        const int ko = (t + 2) * 64;
        const bool pf = (t + 2 < NT);

        if (pf) {
            GLDS16(aSrc[0] + ko, Asb + aDst[0]);
            GLDS16(aSrc[1] + ko, Asb + aDst[1]);
            GLDS16(bSrc[0] + ko, Bsb + bDst[0]);
        }
        {
            bf16x8 af[4], bfr[4];
            #pragma unroll
            for (int i = 0; i < 4; i++) {
                af[i]  = *(const bf16x8*)(Ac + aOff[i][0]);
                bfr[i] = *(const bf16x8*)(Bc + bOff[i][0]);
            }
            __builtin_amdgcn_s_setprio(1);
            #pragma unroll
            for (int mi = 0; mi < 4; mi++)
                #pragma unroll
                for (int nj = 0; nj < 4; nj++)
                    acc[mi][nj] = __builtin_amdgcn_mfma_f32_16x16x32_bf16(
                        af[mi], bfr[nj], acc[mi][nj], 0, 0, 0);
            __builtin_amdgcn_s_setprio(0);
        }
        if (pf) {
            GLDS16(aSrc[2] + ko, Asb + aDst[2]);
            GLDS16(aSrc[3] + ko, Asb + aDst[3]);
            GLDS16(bSrc[1] + ko, Bsb + bDst[1]);
        }
        {
            bf16x8 af[4], bfr[4];
            #pragma unroll
            for (int i = 0; i < 4; i++) {
                af[i]  = *(const bf16x8*)(Ac + aOff[i][1]);
                bfr[i] = *(const bf16x8*)(Bc + bOff[i][1]);
            }
            __builtin_amdgcn_s_setprio(1);
            #pragma unroll
            for (int mi = 0; mi < 4; mi++)
                #pragma unroll
                for (int nj = 0; nj < 4; nj++)
                    acc[mi][nj] = __builtin_amdgcn_mfma_f32_16x16x32_bf16(
                        af[mi], bfr[nj], acc[mi][nj], 0, 0, 0);
            __builtin_amdgcn_s_setprio(0);
        }

        cbuf = (cbuf == 2) ? 0 : cbuf + 1;
        sbuf = (sbuf == 2) ? 0 : sbuf + 1;
    }

    const int N0 = bx * 128;
    const int M0 = by * 256;

    if (MODE == 1) {
        // exp(scores)[b][t=n][s=m] via 64KB LDS transpose + rsum atomics
        __syncthreads();
        #pragma unroll
        for (int mi = 0; mi < 4; mi++) {
            const int mq = wm + mi * 16 + lh * 4;
            #pragma unroll
            for (int nj = 0; nj < 4; nj++) {
                const int n = wn + nj * 16 + l15;
                ushort4 hv = {f2bf(__expf(acc[mi][nj][0])),
                              f2bf(__expf(acc[mi][nj][1])),
                              f2bf(__expf(acc[mi][nj][2])),
                              f2bf(__expf(acc[mi][nj][3]))};
                *(ushort4*)((char*)smem + n * 512 +
                            (((mq >> 3) ^ (n & 31)) << 4) + ((mq >> 2) & 1) * 8) = hv;
            }
        }
        __syncthreads();
        #pragma unroll
        for (int p = 0; p < 8; p++) {
            const int n  = p * 16 + (tid >> 5);
            const int gi = tid & 31;
            uint4 v4 = *(const uint4*)((char*)smem + n * 512 +
                                       ((gi ^ (n & 31)) << 4));
            u16* dst = o0 + ((size_t)b * 1024 + N0 + n) * 1024 + M0;
            *(uint4*)(dst + gi * 8) = v4;
            unsigned wd_[4] = {v4.x, v4.y, v4.z, v4.w};
            float rsm = 0.f;
            #pragma unroll
            for (int q = 0; q < 4; q++)
                rsm += __builtin_bit_cast(float, wd_[q] << 16)
                     + __builtin_bit_cast(float, wd_[q] & 0xffff0000u);
            #pragma unroll
            for (int off = 1; off < 32; off <<= 1)
                rsm += __shfl_xor(rsm, off);
            if (gi == 0)
                atomicAdd(fo + ((size_t)b * 1024 + N0 + n), rsm);
        }
    } else if (N0 < 1024) {
        // q or k: [B,T,C] direct scalar stores; block covers full 128-n span
        u16* dst = (N0 < 512) ? o0 : o1;
        const int nn0 = N0 & 511;
        #pragma unroll
        for (int nj = 0; nj < 4; nj++) {
            const int n = wn + nj * 16 + l15;
            const float bv = bias[N0 + n];
            #pragma unroll
            for (int mi = 0; mi < 4; mi++) {
                const int mq = M0 + wm + mi * 16 + lh * 4;
                const size_t base = ((size_t)b * 1024 + mq) * 512 + nn0 + n;
                dst[base]        = f2bf(acc[mi][nj][0] + bv);
                dst[base + 512]  = f2bf(acc[mi][nj][1] + bv);
                dst[base + 1024] = f2bf(acc[mi][nj][2] + bv);
                dst[base + 1536] = f2bf(acc[mi][nj][3] + bv);
            }
        }
    } else {
        // v: [B,C,T] via LDS transpose, 512B-row coalesced stores
        __syncthreads();
        #pragma unroll
        for (int mi = 0; mi < 4; mi++) {
            const int mq = wm + mi * 16 + lh * 4;
            #pragma unroll
            for (int nj = 0; nj < 4; nj++) {
                const int n = wn + nj * 16 + l15;
                const float bv = bias[N0 + n];
                ushort4 hv = {f2bf(acc[mi][nj][0] + bv), f2bf(acc[mi][nj][1] + bv),
                              f2bf(acc[mi][nj][2] + bv), f2bf(acc[mi][nj][3] + bv)};
                *(ushort4*)((char*)smem + n * 512 +
                            (((mq >> 3) ^ (n & 31)) << 4) + ((mq >> 2) & 1) * 8) = hv;
            }
        }
        __syncthreads();
        #pragma unroll
        for (int p = 0; p < 8; p++) {
            const int n  = p * 16 + (tid >> 5);
            const int gi = tid & 31;
            uint4 v4 = *(const uint4*)((char*)smem + n * 512 +
                                       ((gi ^ (n & 31)) << 4));
            u16* dst = o2 + ((size_t)b * 512 + (N0 - 1024) + n) * 1024 + M0;
            *(uint4*)(dst + gi * 8) = v4;
        }
    }
}

// ---------------------------------------------------------------------------
// 128x128 NT GEMM (r9-proven, GEMM3/GEMM4): 16x16x32 MFMA 16-row frags
// (conflict-free: 131K vs 3.28M cycles), 256 thr, 4 blocks/CU.
// C/D layout (m89): col=lane&15, row=(lane>>4)*4+reg.
// MODE 2: h2[b][t=n][c=m] LDS-transpose (1/rsum scale via xres)
// MODE 3: fp32 out[B,C,T] = acc + bias[n] + x, 2-round LDS-transpose
// ---------------------------------------------------------------------------
template <int MODE>
__global__ __launch_bounds__(256, 4) void gemm128(
    const u16* __restrict__ A, const u16* __restrict__ B,
    size_t strideA, size_t strideB, int lda, int ldb, int K,
    u16* __restrict__ o0,
    float* __restrict__ fo, const float* __restrict__ bias,
    const float* __restrict__ xres)
{
    __shared__ __align__(16) u16 sm[16384];   // As | Bs during loop; C-tile after
    u16* As = sm;
    u16* Bs = sm + 8192;

    const int tid  = threadIdx.x;
    const int lane = tid & 63;
    const int wave = tid >> 6;
    const int wm   = (wave >> 1) * 64;
    const int wn   = (wave & 1) * 64;
    const int l15  = lane & 15;
    const int lh   = lane >> 4;
    const int rx   = lane & 7;

    const int gx = gridDim.x, gy = gridDim.y;
    int f = blockIdx.x + gx * (blockIdx.y + gy * blockIdx.z);
    const int nwg = gx * gy * (int)gridDim.z;
    f = (f & 7) * (nwg >> 3) + (f >> 3);
    const int bx  = f % gx;
    const int byz = f / gx;
    const int by  = byz % gy;
    const int b   = byz / gy;

    const u16* Ab = A + (size_t)b * strideA + (size_t)by * 128 * lda;
    const u16* Bb = B + (size_t)b * strideB + (size_t)bx * 128 * ldb;

    const int srow = lane >> 3;           // 0..7
    const int sc   = lane & 7;
    const int scg  = sc ^ srow;

    int aOff[4][2], bOff[4][2];
    #pragma unroll
    for (int i = 0; i < 4; i++)
        #pragma unroll
        for (int ks = 0; ks < 2; ks++) {
            const int slot = ((ks << 2) + lh) ^ rx;
            aOff[i][ks] = (wm + i * 16 + l15) * 64 + slot * 8;
            bOff[i][ks] = (wn + i * 16 + l15) * 64 + slot * 8;
        }

    f32x4 acc[4][4] = {};

    for (int k0 = 0; k0 < K; k0 += 64) {
        __syncthreads();
        #pragma unroll
        for (int s = 0; s < 4; s++) {
            const int r = wave * 32 + s * 8 + srow;
            GLDS16(Ab + (size_t)r * lda + k0 + scg * 8, As + r * 64 + sc * 8);
            GLDS16(Bb + (size_t)r * ldb + k0 + scg * 8, Bs + r * 64 + sc * 8);
        }
        __syncthreads();

        #pragma unroll
        for (int ks = 0; ks < 2; ks++) {
            bf16x8 af[4], bfr[4];
            #pragma unroll
            for (int i = 0; i < 4; i++) {
                af[i]  = *(const bf16x8*)(As + aOff[i][ks]);
                bfr[i] = *(const bf16x8*)(Bs + bOff[i][ks]);
            }
            __builtin_amdgcn_s_setprio(1);
            #pragma unroll
            for (int mi = 0; mi < 4; mi++)
                #pragma unroll
                for (int nj = 0; nj < 4; nj++)
                    acc[mi][nj] = __builtin_amdgcn_mfma_f32_16x16x32_bf16(
                        af[mi], bfr[nj], acc[mi][nj], 0, 0, 0);
            __builtin_amdgcn_s_setprio(0);
        }
    }

    const int N0 = bx * 128;
    const int M0 = by * 128;

    if (MODE != 3) {
        // stage bf16 C-tile [n:128][m:128] (32 KB), 16B-granule XOR swizzle
        __syncthreads();
        float rinv_[4];
        if (MODE == 2) {
            #pragma unroll
            for (int nj = 0; nj < 4; nj++)
                rinv_[nj] = 1.0f / xres[(size_t)b * 1024 + N0 + wn + nj * 16 + l15];
        }
        #pragma unroll
        for (int mi = 0; mi < 4; mi++) {
            const int mq  = wm + mi * 16 + lh * 4;      // multiple of 4
            const int gsl = mq >> 3;
            const int gb  = ((mq >> 2) & 1) * 8;
            #pragma unroll
            for (int nj = 0; nj < 4; nj++) {
                const int n = wn + nj * 16 + l15;
                float a0 = acc[mi][nj][0], a1 = acc[mi][nj][1];
                float a2 = acc[mi][nj][2], a3 = acc[mi][nj][3];
                if (MODE == 2) {
                    a0 *= rinv_[nj]; a1 *= rinv_[nj];
                    a2 *= rinv_[nj]; a3 *= rinv_[nj];
                }
                ushort4 hv = {f2bf(a0), f2bf(a1), f2bf(a2), f2bf(a3)};
                *(ushort4*)((char*)sm + n * 256 +
                            ((gsl ^ (n & 15)) << 4) + gb) = hv;
            }
        }
        __syncthreads();
        #pragma unroll
        for (int p = 0; p < 8; p++) {
            const int n  = p * 16 + (tid >> 4);
            const int gi = tid & 15;
            uint4 v = *(const uint4*)((char*)sm + n * 256 + ((gi ^ (n & 15)) << 4));
            u16* dst = o0 + ((size_t)b * 1024 + N0 + n) * 512 + M0;
            *(uint4*)(dst + gi * 8) = v;
        }
    } else {
        // MODE 3: fp32 [n:128][m-half:64] tile (32 KB), two rounds by m-half
        float* smf = (float*)sm;
        #pragma unroll
        for (int half = 0; half < 2; half++) {
            __syncthreads();
            if ((wave >> 1) == half) {
                #pragma unroll
                for (int mi = 0; mi < 4; mi++) {
                    const int mloc = mi * 16 + lh * 4;      // 0..63, mult of 4
                    const int gsl  = mloc >> 2;             // 16B granule 0..15
                    #pragma unroll
                    for (int nj = 0; nj < 4; nj++) {
                        const int n = wn + nj * 16 + l15;
                        float4 v4 = {acc[mi][nj][0], acc[mi][nj][1],
                                     acc[mi][nj][2], acc[mi][nj][3]};
                        *(float4*)((char*)smf + n * 256 +
                                   ((gsl ^ (n & 15)) << 4)) = v4;
                    }
                }
            }
            __syncthreads();
            #pragma unroll
            for (int p = 0; p < 8; p++) {
                const int n  = p * 16 + (tid >> 4);
                const int gi = tid & 15;
                float4 v = *(const float4*)((char*)smf + n * 256 +
                                            ((gi ^ (n & 15)) << 4));
                const int m = half * 64 + gi * 4;
                const size_t off = ((size_t)b * 512 + N0 + n) * 1024 + M0 + m;
                const float bv = bias[N0 + n];
                const float4 xv = *(const float4*)(xres + off);
                float4 ov = {v.x + bv + xv.x, v.y + bv + xv.y,
                             v.z + bv + xv.z, v.w + bv + xv.w};
                *(float4*)(fo + off) = ov;
            }
        }
    }
}

// ---------------------------------------------------------------------------
extern "C" void kernel_launch(void* const* d_in, const int* in_sizes, int n_in,
                              void* d_out, int out_size, void* d_ws, size_t ws_size,
                              hipStream_t stream)
{
    const float* x     = (const float*)d_in[0];
    const float* gamma = (const float*)d_in[1];
    const float* beta  = (const float*)d_in[2];
    const float* Wq    = (const float*)d_in[3];
    const float* bq    = (const float*)d_in[4];
    const float* Wk    = (const float*)d_in[5];
    const float* bk    = (const float*)d_in[6];
    const float* Wv    = (const float*)d_in[7];
    const float* bv    = (const float*)d_in[8];
    const float* Wp    = (const float*)d_in[9];
    const float* bp    = (const float*)d_in[10];

    char* ws = (char*)d_ws;
    u16*   Wqkv   = (u16*)(ws + 0);           //  1,572,864 B
    u16*   Wpb    = (u16*)(ws + 1572864);     //    524,288 B
    float* bqkv   = (float*)(ws + 2097152);   //      8,192 B
    u16*   ht     = (u16*)(ws + 2105344);     // 16,777,216 B (reused as h2)
    u16*   kt     = (u16*)(ws + 18882560);    // 16,777,216 B
    u16*   vv     = (u16*)(ws + 35659776);    // 16,777,216 B
    u16*   scores = (u16*)(ws + 52436992);    // 33,554,432 B bf16 (holds exp(s))
    // total ws: 85,991,424 B
    u16*   qt  = (u16*)d_out;   // scratch: q [B,T,C] bf16 (first 16.8MB)
    float* rsum   = (float*)((char*)d_out + 16781312);   // 64KB scratch
    u16*   h2  = ht;
    float* out = (float*)d_out;

    // preamble: convert + bqkv + rsum-init + single-pass GroupNorm -> ht
    gn_fused<<<512, 256, 0, stream>>>(Wq, Wk, Wv, Wp, bq, bk, bv,
                                      x, gamma, beta,
                                      Wqkv, Wpb, bqkv, rsum, ht);

    // GEMM1 qkv (pipelined 256x128): M=1024 N=1536 K=512 ; 768 blocks
    gemm_big<0><<<dim3(12, 4, 16), 512, 0, stream>>>(
        ht, Wqkv, 524288, 0, 512, 512, 512,
        qt, kt, vv, nullptr, bqkv);

    // GEMM2 scores (pipelined 256x128): M=1024(S) N=1024(T) K=512 ; 512 blocks
    // writes P' = exp(s) and accumulates rsum[b][t]
    gemm_big<1><<<dim3(8, 4, 16), 512, 0, stream>>>(
        kt, qt, 524288, 524288, 512, 512, 512,
        scores, nullptr, nullptr, rsum, nullptr);

    // GEMM3 pv (128^2, conflict-free frags): M=512(C) N=1024(T) K=1024(S)
    gemm128<2><<<dim3(8, 4, 16), 256, 0, stream>>>(
        vv, scores, 524288, 1048576, 1024, 1024, 1024,
        h2, nullptr, nullptr, rsum);

    // GEMM4 proj+residual (128^2): M=1024(T) N=512(C) K=512 ; 512 blocks
    gemm128<3><<<dim3(4, 8, 16), 256, 0, stream>>>(
        h2, Wpb, 524288, 0, 512, 512, 512,
        nullptr, out, bp, x);
}

// Round 13
// 202.704 us; speedup vs baseline: 1.2351x; 1.0600x over previous
//
#include <hip/hip_runtime.h>

typedef unsigned short u16;
typedef __bf16 bf16x8 __attribute__((ext_vector_type(8)));
typedef float f32x4 __attribute__((ext_vector_type(4)));

__device__ __forceinline__ u16 f2bf(float f) {
    unsigned u = __builtin_bit_cast(unsigned, f);
    u += 0x7fffu + ((u >> 16) & 1u);
    return (u16)(u >> 16);
}
__device__ __forceinline__ float bf2f(u16 h) {
    return __builtin_bit_cast(float, (unsigned)h << 16);
}

#define GLDS16(g, l) __builtin_amdgcn_global_load_lds( \
    (const __attribute__((address_space(1))) void*)(g), \
    (__attribute__((address_space(3))) void*)(l), 16, 0, 0)

#define QK_SCALE 0.044194173824159216f

// ---------------------------------------------------------------------------
// Fused preamble (ONE kernel, 512 blocks = one per (b, group)):
//   * weight convert fp32->bf16 (8 elems/thread, disjoint ride-along)
//   * bqkv concat + rsum zero-init
//   * GroupNorm single-pass: LDS-cache the (b,g) 16c x 1024t slice (64 KB),
//     stats from registers during load, normalize from LDS, write ht.
// x is read ONCE; ht write = 32B/t segments (L2 RMW ~17MB accepted).
// ---------------------------------------------------------------------------
__global__ __launch_bounds__(256) void gn_fused(
    const float* __restrict__ Wq, const float* __restrict__ Wk,
    const float* __restrict__ Wv, const float* __restrict__ Wp,
    const float* __restrict__ bq, const float* __restrict__ bk,
    const float* __restrict__ bv,
    const float* __restrict__ x, const float* __restrict__ gamma,
    const float* __restrict__ beta,
    u16* __restrict__ Wqkv, u16* __restrict__ Wpb, float* __restrict__ bqkv,
    float* __restrict__ rsum, u16* __restrict__ ht)
{
    __shared__ float xs[16 * 1024];          // 64 KB slice [c:16][t:1024]
    __shared__ float rs[4], rs2[4], stat2[2];

    const int tid  = threadIdx.x;
    const int blk  = blockIdx.x;             // 0..511
    const int gidx = blk * 256 + tid;        // 0..131071

    // ---- weight convert: 8 consecutive elems per thread (exact cover) ----
    {
        const int base  = gidx * 8;          // 0..1048568; boundaries % 8 == 0
        const int which = base >> 18;        // 0:Wq 1:Wk 2:Wv 3:Wp
        const int off   = base & 262143;
        const float* src = (which == 0) ? Wq + off
                         : (which == 1) ? Wk + off
                         : (which == 2) ? Wv + off : Wp + off;
        const float sc = (which == 0) ? QK_SCALE : 1.0f;
        float4 a = ((const float4*)src)[0];
        float4 c = ((const float4*)src)[1];
        u16 h[8] = {f2bf(a.x * sc), f2bf(a.y * sc), f2bf(a.z * sc), f2bf(a.w * sc),
                    f2bf(c.x * sc), f2bf(c.y * sc), f2bf(c.z * sc), f2bf(c.w * sc)};
        if (which < 3) *(uint4*)(Wqkv + base) = *(uint4*)h;
        else           *(uint4*)(Wpb + (base - 786432)) = *(uint4*)h;
    }
    if (gidx < 1536) {
        bqkv[gidx] = (gidx < 512) ? bq[gidx] * QK_SCALE
                   : (gidx < 1024) ? bk[gidx & 511] : bv[gidx & 511];
    }
    if (gidx < 16384) rsum[gidx] = 0.f;

    // ---- GN: load slice to LDS, accumulate stats in-flight ----
    const int b = blk >> 5, g = blk & 31;
    const float4* xg4 = (const float4*)(x + ((size_t)b * 512 + (size_t)g * 16) * 1024);
    float4* xs4 = (float4*)xs;
    float s = 0.f, s2 = 0.f;
    #pragma unroll
    for (int i = 0; i < 16; i++) {
        float4 v = xg4[i * 256 + tid];
        xs4[i * 256 + tid] = v;
        s  += v.x + v.y + v.z + v.w;
        s2 += v.x * v.x + v.y * v.y + v.z * v.z + v.w * v.w;
    }
    #pragma unroll
    for (int off = 32; off; off >>= 1) {
        s  += __shfl_down(s, off);
        s2 += __shfl_down(s2, off);
    }
    const int w = tid >> 6;
    if ((tid & 63) == 0) { rs[w] = s; rs2[w] = s2; }
    __syncthreads();
    if (tid == 0) {
        float S  = rs[0] + rs[1] + rs[2] + rs[3];
        float S2 = rs2[0] + rs2[1] + rs2[2] + rs2[3];
        float mean = S * (1.f / 16384.f);
        float var  = S2 * (1.f / 16384.f) - mean * mean;
        stat2[0] = mean;
        stat2[1] = rsqrtf(var + 1e-5f);
    }
    __syncthreads();
    const float mean = stat2[0], rstd = stat2[1];

    float scl[16], shf[16];
    #pragma unroll
    for (int c = 0; c < 16; c++) {
        float ga = gamma[g * 16 + c];
        scl[c] = rstd * ga;
        shf[c] = beta[g * 16 + c] - mean * scl[c];
    }

    // ---- apply from LDS + write ht[b][t][g*16..+16) (32B per t) ----
    #pragma unroll
    for (int i = 0; i < 4; i++) {
        const int t = i * 256 + tid;
        u16 h[16];
        #pragma unroll
        for (int c = 0; c < 16; c++)
            h[c] = f2bf(xs[c * 1024 + t] * scl[c] + shf[c]);
        uint4* d = (uint4*)(ht + ((size_t)b * 1024 + t) * 512 + g * 16);
        d[0] = ((uint4*)h)[0];
        d[1] = ((uint4*)h)[1];
    }
}

// ---------------------------------------------------------------------------
// Pipelined NT GEMM (r4-proven): BM=256 BN=128 BK=64, 8 waves, 3 LDS bufs,
// counted vmcnt(6), 1 barrier/K-tile, 2 ks-phases, setprio around MFMA.
// MODE 0: qkv (q,k [B,T,C] direct; v [B,C,T] LDS-transpose) + bias.
// MODE 1: exp(scores)[b][t=n][s=m] LDS-transpose + rsum atomics (via fo).
// ---------------------------------------------------------------------------
template <int MODE>
__global__ __launch_bounds__(512, 2) void gemm_big(
    const u16* __restrict__ A, const u16* __restrict__ B,
    size_t strideA, size_t strideB, int lda, int ldb, int K,
    u16* __restrict__ o0, u16* __restrict__ o1, u16* __restrict__ o2,
    float* __restrict__ fo, const float* __restrict__ bias)
{
    __shared__ __align__(16) u16 smem[73728];   // 144 KB
    u16* As = smem;                  // 3 x 16384 elems (256x64)
    u16* Bs = smem + 49152;          // 3 x  8192 elems (128x64)

    const int tid  = threadIdx.x;
    const int lane = tid & 63;
    const int wave = tid >> 6;
    const int wm   = (wave & 3) * 64;
    const int wn   = (wave >> 2) * 64;

    const int gx = gridDim.x, gy = gridDim.y;
    int f = blockIdx.x + gx * (blockIdx.y + gy * blockIdx.z);
    const int nwg = gx * gy * (int)gridDim.z;
    f = (f & 7) * (nwg >> 3) + (f >> 3);
    const int bx  = f % gx;
    const int byz = f / gx;
    const int by  = byz % gy;
    const int b   = byz / gy;

    const u16* Ab = A + (size_t)b * strideA + (size_t)by * 256 * lda;
    const u16* Bb = B + (size_t)b * strideB + (size_t)bx * 128 * ldb;

    const int srow = tid >> 3;
    const int sc   = tid & 7;
    const int scg  = sc ^ (srow & 7);

    const u16* aSrc[4]; int aDst[4];
    #pragma unroll
    for (int u = 0; u < 4; u++) {
        aSrc[u] = Ab + (size_t)(u * 64 + srow) * lda + scg * 8;
        aDst[u] = (u * 64 + srow) * 64 + sc * 8;
    }
    const u16* bSrc[2]; int bDst[2];
    #pragma unroll
    for (int u = 0; u < 2; u++) {
        bSrc[u] = Bb + (size_t)(u * 64 + srow) * ldb + scg * 8;
        bDst[u] = (u * 64 + srow) * 64 + sc * 8;
    }

    const int l15 = lane & 15, lh = lane >> 4, rx = lane & 7;
    int aOff[4][2], bOff[4][2];
    #pragma unroll
    for (int i = 0; i < 4; i++)
        #pragma unroll
        for (int ks = 0; ks < 2; ks++) {
            const int slot = ((ks << 2) + lh) ^ rx;
            aOff[i][ks] = (wm + i * 16 + l15) * 64 + slot * 8;
            bOff[i][ks] = (wn + i * 16 + l15) * 64 + slot * 8;
        }

    f32x4 acc[4][4] = {};
    const int NT = K >> 6;

    #pragma unroll
    for (int u = 0; u < 4; u++) GLDS16(aSrc[u], As + aDst[u]);
    #pragma unroll
    for (int u = 0; u < 2; u++) GLDS16(bSrc[u], Bs + bDst[u]);
    #pragma unroll
    for (int u = 0; u < 4; u++) GLDS16(aSrc[u] + 64, As + 16384 + aDst[u]);
    #pragma unroll
    for (int u = 0; u < 2; u++) GLDS16(bSrc[u] + 64, Bs + 8192 + bDst[u]);

    int cbuf = 0, sbuf = 2;
    for (int t = 0; t < NT; ++t) {
        if (t == NT - 1) asm volatile("s_waitcnt vmcnt(0)" ::: "memory");
        else             asm volatile("s_waitcnt vmcnt(6)" ::: "memory");
        __builtin_amdgcn_s_barrier();

        const u16* Ac = As + cbuf * 16384;
        const u16* Bc = Bs + cbuf * 8192;
        u16* Asb = As + sbuf * 16384;
        u16* Bsb = Bs + sbuf * 8192;
        const int ko = (t + 2) * 64;
        const bool pf = (t + 2 < NT);

        if (pf) {
            GLDS16(aSrc[0] + ko, Asb + aDst[0]);
            GLDS16(aSrc[1] + ko, Asb + aDst[1]);
            GLDS16(bSrc[0] + ko, Bsb + bDst[0]);
        }
        {
            bf16x8 af[4], bfr[4];
            #pragma unroll
            for (int i = 0; i < 4; i++) {
                af[i]  = *(const bf16x8*)(Ac + aOff[i][0]);
                bfr[i] = *(const bf16x8*)(Bc + bOff[i][0]);
            }
            __builtin_amdgcn_s_setprio(1);
            #pragma unroll
            for (int mi = 0; mi < 4; mi++)
                #pragma unroll
                for (int nj = 0; nj < 4; nj++)
                    acc[mi][nj] = __builtin_amdgcn_mfma_f32_16x16x32_bf16(
                        af[mi], bfr[nj], acc[mi][nj], 0, 0, 0);
            __builtin_amdgcn_s_setprio(0);
        }
        if (pf) {
            GLDS16(aSrc[2] + ko, Asb + aDst[2]);
            GLDS16(aSrc[3] + ko, Asb + aDst[3]);
            GLDS16(bSrc[1] + ko, Bsb + bDst[1]);
        }
        {
            bf16x8 af[4], bfr[4];
            #pragma unroll
            for (int i = 0; i < 4; i++) {
                af[i]  = *(const bf16x8*)(Ac + aOff[i][1]);
                bfr[i] = *(const bf16x8*)(Bc + bOff[i][1]);
            }
            __builtin_amdgcn_s_setprio(1);
            #pragma unroll
            for (int mi = 0; mi < 4; mi++)
                #pragma unroll
                for (int nj = 0; nj < 4; nj++)
                    acc[mi][nj] = __builtin_amdgcn_mfma_f32_16x16x32_bf16(
                        af[mi], bfr[nj], acc[mi][nj], 0, 0, 0);
            __builtin_amdgcn_s_setprio(0);
        }

        cbuf = (cbuf == 2) ? 0 : cbuf + 1;
        sbuf = (sbuf == 2) ? 0 : sbuf + 1;
    }

    const int N0 = bx * 128;
    const int M0 = by * 256;

    if (MODE == 1) {
        // exp(scores)[b][t=n][s=m] via 64KB LDS transpose + rsum atomics
        __syncthreads();
        #pragma unroll
        for (int mi = 0; mi < 4; mi++) {
            const int mq = wm + mi * 16 + lh * 4;
            #pragma unroll
            for (int nj = 0; nj < 4; nj++) {
                const int n = wn + nj * 16 + l15;
                ushort4 hv = {f2bf(__expf(acc[mi][nj][0])),
                              f2bf(__expf(acc[mi][nj][1])),
                              f2bf(__expf(acc[mi][nj][2])),
                              f2bf(__expf(acc[mi][nj][3]))};
                *(ushort4*)((char*)smem + n * 512 +
                            (((mq >> 3) ^ (n & 31)) << 4) + ((mq >> 2) & 1) * 8) = hv;
            }
        }
        __syncthreads();
        #pragma unroll
        for (int p = 0; p < 8; p++) {
            const int n  = p * 16 + (tid >> 5);
            const int gi = tid & 31;
            uint4 v4 = *(const uint4*)((char*)smem + n * 512 +
                                       ((gi ^ (n & 31)) << 4));
            u16* dst = o0 + ((size_t)b * 1024 + N0 + n) * 1024 + M0;
            *(uint4*)(dst + gi * 8) = v4;
            unsigned wd_[4] = {v4.x, v4.y, v4.z, v4.w};
            float rsm = 0.f;
            #pragma unroll
            for (int q = 0; q < 4; q++)
                rsm += __builtin_bit_cast(float, wd_[q] << 16)
                     + __builtin_bit_cast(float, wd_[q] & 0xffff0000u);
            #pragma unroll
            for (int off = 1; off < 32; off <<= 1)
                rsm += __shfl_xor(rsm, off);
            if (gi == 0)
                atomicAdd(fo + ((size_t)b * 1024 + N0 + n), rsm);
        }
    } else if (N0 < 1024) {
        // q or k: [B,T,C] direct scalar stores; block covers full 128-n span
        u16* dst = (N0 < 512) ? o0 : o1;
        const int nn0 = N0 & 511;
        #pragma unroll
        for (int nj = 0; nj < 4; nj++) {
            const int n = wn + nj * 16 + l15;
            const float bv = bias[N0 + n];
            #pragma unroll
            for (int mi = 0; mi < 4; mi++) {
                const int mq = M0 + wm + mi * 16 + lh * 4;
                const size_t base = ((size_t)b * 1024 + mq) * 512 + nn0 + n;
                dst[base]        = f2bf(acc[mi][nj][0] + bv);
                dst[base + 512]  = f2bf(acc[mi][nj][1] + bv);
                dst[base + 1024] = f2bf(acc[mi][nj][2] + bv);
                dst[base + 1536] = f2bf(acc[mi][nj][3] + bv);
            }
        }
    } else {
        // v: [B,C,T] via LDS transpose, 512B-row coalesced stores
        __syncthreads();
        #pragma unroll
        for (int mi = 0; mi < 4; mi++) {
            const int mq = wm + mi * 16 + lh * 4;
            #pragma unroll
            for (int nj = 0; nj < 4; nj++) {
                const int n = wn + nj * 16 + l15;
                const float bv = bias[N0 + n];
                ushort4 hv = {f2bf(acc[mi][nj][0] + bv), f2bf(acc[mi][nj][1] + bv),
                              f2bf(acc[mi][nj][2] + bv), f2bf(acc[mi][nj][3] + bv)};
                *(ushort4*)((char*)smem + n * 512 +
                            (((mq >> 3) ^ (n & 31)) << 4) + ((mq >> 2) & 1) * 8) = hv;
            }
        }
        __syncthreads();
        #pragma unroll
        for (int p = 0; p < 8; p++) {
            const int n  = p * 16 + (tid >> 5);
            const int gi = tid & 31;
            uint4 v4 = *(const uint4*)((char*)smem + n * 512 +
                                       ((gi ^ (n & 31)) << 4));
            u16* dst = o2 + ((size_t)b * 512 + (N0 - 1024) + n) * 1024 + M0;
            *(uint4*)(dst + gi * 8) = v4;
        }
    }
}

// ---------------------------------------------------------------------------
// 128x128 NT GEMM (r9-proven, GEMM3/GEMM4): 16x16x32 MFMA 16-row frags
// (conflict-free: 131K vs 3.28M cycles), 256 thr, 4 blocks/CU.
// C/D layout (m89): col=lane&15, row=(lane>>4)*4+reg.
// MODE 2: h2[b][t=n][c=m] LDS-transpose (1/rsum scale via xres)
// MODE 3: fp32 out[B,C,T] = acc + bias[n] + x, 2-round LDS-transpose
// ---------------------------------------------------------------------------
template <int MODE>
__global__ __launch_bounds__(256, 4) void gemm128(
    const u16* __restrict__ A, const u16* __restrict__ B,
    size_t strideA, size_t strideB, int lda, int ldb, int K,
    u16* __restrict__ o0,
    float* __restrict__ fo, const float* __restrict__ bias,
    const float* __restrict__ xres)
{
    __shared__ __align__(16) u16 sm[16384];   // As | Bs during loop; C-tile after
    u16* As = sm;
    u16* Bs = sm + 8192;

    const int tid  = threadIdx.x;
    const int lane = tid & 63;
    const int wave = tid >> 6;
    const int wm   = (wave >> 1) * 64;
    const int wn   = (wave & 1) * 64;
    const int l15  = lane & 15;
    const int lh   = lane >> 4;
    const int rx   = lane & 7;

    const int gx = gridDim.x, gy = gridDim.y;
    int f = blockIdx.x + gx * (blockIdx.y + gy * blockIdx.z);
    const int nwg = gx * gy * (int)gridDim.z;
    f = (f & 7) * (nwg >> 3) + (f >> 3);
    const int bx  = f % gx;
    const int byz = f / gx;
    const int by  = byz % gy;
    const int b   = byz / gy;

    const u16* Ab = A + (size_t)b * strideA + (size_t)by * 128 * lda;
    const u16* Bb = B + (size_t)b * strideB + (size_t)bx * 128 * ldb;

    const int srow = lane >> 3;           // 0..7
    const int sc   = lane & 7;
    const int scg  = sc ^ srow;

    int aOff[4][2], bOff[4][2];
    #pragma unroll
    for (int i = 0; i < 4; i++)
        #pragma unroll
        for (int ks = 0; ks < 2; ks++) {
            const int slot = ((ks << 2) + lh) ^ rx;
            aOff[i][ks] = (wm + i * 16 + l15) * 64 + slot * 8;
            bOff[i][ks] = (wn + i * 16 + l15) * 64 + slot * 8;
        }

    f32x4 acc[4][4] = {};

    for (int k0 = 0; k0 < K; k0 += 64) {
        __syncthreads();
        #pragma unroll
        for (int s = 0; s < 4; s++) {
            const int r = wave * 32 + s * 8 + srow;
            GLDS16(Ab + (size_t)r * lda + k0 + scg * 8, As + r * 64 + sc * 8);
            GLDS16(Bb + (size_t)r * ldb + k0 + scg * 8, Bs + r * 64 + sc * 8);
        }
        __syncthreads();

        #pragma unroll
        for (int ks = 0; ks < 2; ks++) {
            bf16x8 af[4], bfr[4];
            #pragma unroll
            for (int i = 0; i < 4; i++) {
                af[i]  = *(const bf16x8*)(As + aOff[i][ks]);
                bfr[i] = *(const bf16x8*)(Bs + bOff[i][ks]);
            }
            __builtin_amdgcn_s_setprio(1);
            #pragma unroll
            for (int mi = 0; mi < 4; mi++)
                #pragma unroll
                for (int nj = 0; nj < 4; nj++)
                    acc[mi][nj] = __builtin_amdgcn_mfma_f32_16x16x32_bf16(
                        af[mi], bfr[nj], acc[mi][nj], 0, 0, 0);
            __builtin_amdgcn_s_setprio(0);
        }
    }

    const int N0 = bx * 128;
    const int M0 = by * 128;

    if (MODE != 3) {
        // stage bf16 C-tile [n:128][m:128] (32 KB), 16B-granule XOR swizzle
        __syncthreads();
        float rinv_[4];
        if (MODE == 2) {
            #pragma unroll
            for (int nj = 0; nj < 4; nj++)
                rinv_[nj] = 1.0f / xres[(size_t)b * 1024 + N0 + wn + nj * 16 + l15];
        }
        #pragma unroll
        for (int mi = 0; mi < 4; mi++) {
            const int mq  = wm + mi * 16 + lh * 4;      // multiple of 4
            const int gsl = mq >> 3;
            const int gb  = ((mq >> 2) & 1) * 8;
            #pragma unroll
            for (int nj = 0; nj < 4; nj++) {
                const int n = wn + nj * 16 + l15;
                float a0 = acc[mi][nj][0], a1 = acc[mi][nj][1];
                float a2 = acc[mi][nj][2], a3 = acc[mi][nj][3];
                if (MODE == 2) {
                    a0 *= rinv_[nj]; a1 *= rinv_[nj];
                    a2 *= rinv_[nj]; a3 *= rinv_[nj];
                }
                ushort4 hv = {f2bf(a0), f2bf(a1), f2bf(a2), f2bf(a3)};
                *(ushort4*)((char*)sm + n * 256 +
                            ((gsl ^ (n & 15)) << 4) + gb) = hv;
            }
        }
        __syncthreads();
        #pragma unroll
        for (int p = 0; p < 8; p++) {
            const int n  = p * 16 + (tid >> 4);
            const int gi = tid & 15;
            uint4 v = *(const uint4*)((char*)sm + n * 256 + ((gi ^ (n & 15)) << 4));
            u16* dst = o0 + ((size_t)b * 1024 + N0 + n) * 512 + M0;
            *(uint4*)(dst + gi * 8) = v;
        }
    } else {
        // MODE 3: fp32 [n:128][m-half:64] tile (32 KB), two rounds by m-half
        float* smf = (float*)sm;
        #pragma unroll
        for (int half = 0; half < 2; half++) {
            __syncthreads();
            if ((wave >> 1) == half) {
                #pragma unroll
                for (int mi = 0; mi < 4; mi++) {
                    const int mloc = mi * 16 + lh * 4;      // 0..63, mult of 4
                    const int gsl  = mloc >> 2;             // 16B granule 0..15
                    #pragma unroll
                    for (int nj = 0; nj < 4; nj++) {
                        const int n = wn + nj * 16 + l15;
                        float4 v4 = {acc[mi][nj][0], acc[mi][nj][1],
                                     acc[mi][nj][2], acc[mi][nj][3]};
                        *(float4*)((char*)smf + n * 256 +
                                   ((gsl ^ (n & 15)) << 4)) = v4;
                    }
                }
            }
            __syncthreads();
            #pragma unroll
            for (int p = 0; p < 8; p++) {
                const int n  = p * 16 + (tid >> 4);
                const int gi = tid & 15;
                float4 v = *(const float4*)((char*)smf + n * 256 +
                                            ((gi ^ (n & 15)) << 4));
                const int m = half * 64 + gi * 4;
                const size_t off = ((size_t)b * 512 + N0 + n) * 1024 + M0 + m;
                const float bv = bias[N0 + n];
                const float4 xv = *(const float4*)(xres + off);
                float4 ov = {v.x + bv + xv.x, v.y + bv + xv.y,
                             v.z + bv + xv.z, v.w + bv + xv.w};
                *(float4*)(fo + off) = ov;
            }
        }
    }
}

// ---------------------------------------------------------------------------
extern "C" void kernel_launch(void* const* d_in, const int* in_sizes, int n_in,
                              void* d_out, int out_size, void* d_ws, size_t ws_size,
                              hipStream_t stream)
{
    const float* x     = (const float*)d_in[0];
    const float* gamma = (const float*)d_in[1];
    const float* beta  = (const float*)d_in[2];
    const float* Wq    = (const float*)d_in[3];
    const float* bq    = (const float*)d_in[4];
    const float* Wk    = (const float*)d_in[5];
    const float* bk    = (const float*)d_in[6];
    const float* Wv    = (const float*)d_in[7];
    const float* bv    = (const float*)d_in[8];
    const float* Wp    = (const float*)d_in[9];
    const float* bp    = (const float*)d_in[10];

    char* ws = (char*)d_ws;
    u16*   Wqkv   = (u16*)(ws + 0);           //  1,572,864 B
    u16*   Wpb    = (u16*)(ws + 1572864);     //    524,288 B
    float* bqkv   = (float*)(ws + 2097152);   //      8,192 B
    u16*   ht     = (u16*)(ws + 2105344);     // 16,777,216 B (reused as h2)
    u16*   kt     = (u16*)(ws + 18882560);    // 16,777,216 B
    u16*   vv     = (u16*)(ws + 35659776);    // 16,777,216 B
    u16*   scores = (u16*)(ws + 52436992);    // 33,554,432 B bf16 (holds exp(s))
    // total ws: 85,991,424 B
    u16*   qt  = (u16*)d_out;   // scratch: q [B,T,C] bf16 (first 16.8MB)
    float* rsum   = (float*)((char*)d_out + 16781312);   // 64KB scratch
    u16*   h2  = ht;
    float* out = (float*)d_out;

    // preamble: convert + bqkv + rsum-init + single-pass GroupNorm -> ht
    gn_fused<<<512, 256, 0, stream>>>(Wq, Wk, Wv, Wp, bq, bk, bv,
                                      x, gamma, beta,
                                      Wqkv, Wpb, bqkv, rsum, ht);

    // GEMM1 qkv (pipelined 256x128): M=1024 N=1536 K=512 ; 768 blocks
    gemm_big<0><<<dim3(12, 4, 16), 512, 0, stream>>>(
        ht, Wqkv, 524288, 0, 512, 512, 512,
        qt, kt, vv, nullptr, bqkv);

    // GEMM2 scores (pipelined 256x128): M=1024(S) N=1024(T) K=512 ; 512 blocks
    // writes P' = exp(s) and accumulates rsum[b][t]
    gemm_big<1><<<dim3(8, 4, 16), 512, 0, stream>>>(
        kt, qt, 524288, 524288, 512, 512, 512,
        scores, nullptr, nullptr, rsum, nullptr);

    // GEMM3 pv (128^2, conflict-free frags): M=512(C) N=1024(T) K=1024(S)
    gemm128<2><<<dim3(8, 4, 16), 256, 0, stream>>>(
        vv, scores, 524288, 1048576, 1024, 1024, 1024,
        h2, nullptr, nullptr, rsum);

    // GEMM4 proj+residual (128^2): M=1024(T) N=512(C) K=512 ; 512 blocks
    gemm128<3><<<dim3(4, 8, 16), 256, 0, stream>>>(
        h2, Wpb, 524288, 0, 512, 512, 512,
        nullptr, out, bp, x);
}